// Round 3
// baseline (548.228 us; speedup 1.0000x reference)
//
#include <hip/hip_runtime.h>
#include <math.h>

// GCN: h = elu(D^-1/2 (A+I) D^-1/2 (h W) + b [+ resid])
// N=100000 nodes, E=1600000 edges, 128 features per layer.
//
// R10 changes vs R9: XCD-sharded feature-split aggregate.
//  - R9 evidence: FETCH pinned at 213.8MB = per-XCD compulsory floor
//    (each XCD gathers the whole 25.6MB table once: 8 x 25.6 = 205MB).
//    MLP deepening gave only -7% -> compulsory-byte-bound, not
//    instruction- or occupancy-bound.
//  - Rows split into two 128B halves. blockIdx%8 == XCD (round-robin
//    dispatch): XCDs 0-3 process half 0, XCDs 4-7 half 1. Per-XCD
//    unique footprint 25.6 -> 12.8MB => table fetch 205 -> 102MB.
//  - Octet-split gathers: 8 lanes x 16B per edge -> 8 edges per VMEM
//    instr; 4 independent gathers in flight (32-edge step).
//  - Wave count doubles (2 halves) -> more TLP on top.
//  - Correctness does NOT depend on the XCD mapping; a different
//    mapping only loses the locality benefit.

#define NFEAT 128
#define LDSP 136   // LDS row pitch in shorts (128 + 8 pad)
#define BSH 9      // bucket shift: 512 nodes/bucket
#define BWID 512

typedef short short8 __attribute__((ext_vector_type(8)));
typedef float f32x4 __attribute__((ext_vector_type(4)));
typedef float f32x2 __attribute__((ext_vector_type(2)));
typedef int i32x4 __attribute__((ext_vector_type(4)));

static __device__ __forceinline__ unsigned short f2bf(float f) {
  union { float f; unsigned int u; } v; v.f = f;
  unsigned int r = v.u + 0x7fffu + ((v.u >> 16) & 1u);  // RNE (finite values)
  return (unsigned short)(r >> 16);
}
static __device__ __forceinline__ float bf2f(unsigned short b) {
  union { unsigned int u; float f; } v; v.u = ((unsigned int)b) << 16;
  return v.f;
}

// ---------------- GEMM body (LDS-staged MFMA) ----------------
// hW_bf16[n,128] = h[n,128] @ W. 64 nodes/block, operand-swapped MFMA so
// each lane stores contiguous ushort4 runs of its own node row.
static __device__ __forceinline__ void gemm_body(
    int gblk, const float* __restrict__ h, const unsigned short* __restrict__ Wt,
    unsigned short* __restrict__ out, int n, unsigned short* lds) {
  int t = threadIdx.x;
  int block0 = gblk * 64;

  const f32x4* h4 = (const f32x4*)h;
  #pragma unroll
  for (int i = 0; i < 8; ++i) {
    int idx = t + 256 * i;          // 0..2047
    int r = idx >> 5, c = idx & 31; // row, float4-col
    int grow = block0 + r; if (grow >= n) grow = n - 1;
    f32x4 v = __builtin_nontemporal_load(&h4[(size_t)grow * 32 + c]);
    ushort4 b;
    b.x = f2bf(v.x); b.y = f2bf(v.y); b.z = f2bf(v.z); b.w = f2bf(v.w);
    *(ushort4*)&lds[r * LDSP + c * 4] = b;
  }
  __syncthreads();

  int lane = t & 63, wave = t >> 6;
  int row16 = lane & 15;
  int kgrp = lane >> 4;

  short8 afrag[4];
  #pragma unroll
  for (int ks = 0; ks < 4; ++ks)
    afrag[ks] =
        *(const short8*)&lds[(wave * 16 + row16) * LDSP + ks * 32 + kgrp * 8];

  f32x4 acc[8];
  #pragma unroll
  for (int ct = 0; ct < 8; ++ct) {
    acc[ct] = (f32x4){0.0f, 0.0f, 0.0f, 0.0f};
    const short8* wrow =
        (const short8*)(Wt + (size_t)(ct * 16 + row16) * NFEAT);
    #pragma unroll
    for (int ks = 0; ks < 4; ++ks) {
      acc[ct] = __builtin_amdgcn_mfma_f32_16x16x32_bf16(
          wrow[ks * 4 + kgrp], afrag[ks], acc[ct], 0, 0, 0);
    }
  }

  int orow = block0 + wave * 16 + row16;
  if (orow < n) {
    unsigned short* op = out + (size_t)orow * NFEAT + kgrp * 4;
    #pragma unroll
    for (int ct = 0; ct < 8; ++ct) {
      ushort4 o;
      o.x = f2bf(acc[ct][0]); o.y = f2bf(acc[ct][1]);
      o.z = f2bf(acc[ct][2]); o.w = f2bf(acc[ct][3]);
      *(ushort4*)(op + ct * 16) = o;
    }
  }
}

__global__ __launch_bounds__(256) void gemm_mfma_kernel(
    const float* __restrict__ h, const unsigned short* __restrict__ Wt,
    unsigned short* __restrict__ out, int n) {
  __shared__ int lds_i[64 * LDSP / 2];
  gemm_body(blockIdx.x, h, Wt, out, n, (unsigned short*)lds_i);
}

// gemm0 fused with Pass A (bucket histogram) — independent work.
__global__ __launch_bounds__(256) void fused_g0_hist_kernel(
    const float* __restrict__ x, const unsigned short* __restrict__ Wt0,
    unsigned short* __restrict__ hWb, int n, int gb,
    const int4* __restrict__ dst4, int* __restrict__ bcnt, int e4, int nbuc) {
  __shared__ int lds_i[64 * LDSP / 2];
  int t = threadIdx.x;
  if ((int)blockIdx.x < gb) {
    gemm_body(blockIdx.x, x, Wt0, hWb, n, (unsigned short*)lds_i);
  } else {
    int* hist = lds_i;
    hist[t] = 0;
    __syncthreads();
    int base = ((int)blockIdx.x - gb) * 1024;
    #pragma unroll
    for (int i = 0; i < 4; ++i) {
      int idx = base + t + 256 * i;
      if (idx < e4) {
        int4 d = dst4[idx];
        atomicAdd(&hist[d.x >> BSH], 1);
        atomicAdd(&hist[d.y >> BSH], 1);
        atomicAdd(&hist[d.z >> BSH], 1);
        atomicAdd(&hist[d.w >> BSH], 1);
      }
    }
    __syncthreads();
    int h = hist[t];
    if (t < nbuc && h) atomicAdd(&bcnt[t], h);
  }
}

// Pass B: exclusive scan of bucket counts (nbuc <= 256), init gcur, rowp[n]=E
__global__ __launch_bounds__(256) void scan_buckets_kernel(
    const int* __restrict__ bcnt, int* __restrict__ boff,
    int* __restrict__ gcur, int* __restrict__ rowp, int nbuc, int n, int e) {
  __shared__ int wsum[4];
  int t = threadIdx.x, lane = t & 63, wid = t >> 6;
  int v = (t < nbuc) ? bcnt[t] : 0;
  int s = v;
  #pragma unroll
  for (int off = 1; off < 64; off <<= 1) {
    int u = __shfl_up(s, off, 64);
    if (lane >= off) s += u;
  }
  if (lane == 63) wsum[wid] = s;
  __syncthreads();
  int add = 0;
  for (int w = 0; w < wid; ++w) add += wsum[w];
  int incl = add + s;
  if (t < nbuc) { boff[t] = incl - v; gcur[t] = incl - v; }
  if (t == nbuc - 1) boff[nbuc] = incl;  // == E
  if (t == 0) rowp[n] = e;
}

// Pass C: scatter (dst,src) u64 into bucket-major ebuf, block-chunked.
__global__ __launch_bounds__(256) void bucket_scatter_kernel(
    const int4* __restrict__ src4, const int4* __restrict__ dst4,
    int* __restrict__ gcur, unsigned long long* __restrict__ ebuf, int e4) {
  __shared__ int hist[256];
  __shared__ int cbase[256];
  __shared__ int cur[256];
  int t = threadIdx.x;
  hist[t] = 0; cur[t] = 0;
  __syncthreads();
  int base = blockIdx.x * 1024;
  int4 dv[4], sv[4];
  bool val[4];
  #pragma unroll
  for (int i = 0; i < 4; ++i) {
    int idx = base + t + 256 * i;
    val[i] = idx < e4;
    if (val[i]) {
      dv[i] = dst4[idx];
      sv[i] = src4[idx];
      atomicAdd(&hist[dv[i].x >> BSH], 1);
      atomicAdd(&hist[dv[i].y >> BSH], 1);
      atomicAdd(&hist[dv[i].z >> BSH], 1);
      atomicAdd(&hist[dv[i].w >> BSH], 1);
    }
  }
  __syncthreads();
  int h = hist[t];
  if (h) cbase[t] = atomicAdd(&gcur[t], h);  // hist[t]==0 for t>=nbuc
  __syncthreads();
  #pragma unroll
  for (int i = 0; i < 4; ++i) {
    if (val[i]) {
      int d, s, b, p;
      d = dv[i].x; s = sv[i].x; b = d >> BSH;
      p = cbase[b] + atomicAdd(&cur[b], 1);
      ebuf[p] = ((unsigned long long)(unsigned)d << 32) | (unsigned)s;
      d = dv[i].y; s = sv[i].y; b = d >> BSH;
      p = cbase[b] + atomicAdd(&cur[b], 1);
      ebuf[p] = ((unsigned long long)(unsigned)d << 32) | (unsigned)s;
      d = dv[i].z; s = sv[i].z; b = d >> BSH;
      p = cbase[b] + atomicAdd(&cur[b], 1);
      ebuf[p] = ((unsigned long long)(unsigned)d << 32) | (unsigned)s;
      d = dv[i].w; s = sv[i].w; b = d >> BSH;
      p = cbase[b] + atomicAdd(&cur[b], 1);
      ebuf[p] = ((unsigned long long)(unsigned)d << 32) | (unsigned)s;
    }
  }
}

// Pass D1: per-bucket degree hist (LDS) + local scan -> rowp, dinv.
__global__ __launch_bounds__(256) void bucket_deg_kernel(
    const unsigned long long* __restrict__ ebuf, const int* __restrict__ boff,
    int* __restrict__ rowp, float* __restrict__ dinv, int n) {
  __shared__ int deg[BWID];
  __shared__ int wsum[4];
  int t = threadIdx.x;
  int b = blockIdx.x, node0 = b << BSH;
  deg[t] = 0; deg[t + 256] = 0;
  __syncthreads();
  int ebeg = boff[b], eend = boff[b + 1];
  for (int i = ebeg + t; i < eend; i += 256) {
    int d = (int)(ebuf[i] >> 32);
    atomicAdd(&deg[d - node0], 1);
  }
  __syncthreads();
  int d0 = deg[2 * t], d1 = deg[2 * t + 1];
  int s = d0 + d1;
  int lane = t & 63, wid = t >> 6;
  int sc = s;
  #pragma unroll
  for (int off = 1; off < 64; off <<= 1) {
    int u = __shfl_up(sc, off, 64);
    if (lane >= off) sc += u;
  }
  if (lane == 63) wsum[wid] = sc;
  __syncthreads();
  int add = 0;
  for (int w = 0; w < wid; ++w) add += wsum[w];
  int excl = ebeg + add + sc - s;  // rowp of node 2t in this bucket
  int node = node0 + 2 * t;
  if (node < n) {
    rowp[node] = excl;
    dinv[node] = rsqrtf(1.0f + (float)d0);
  }
  if (node + 1 < n) {
    rowp[node + 1] = excl + d0;
    dinv[node + 1] = rsqrtf(1.0f + (float)d1);
  }
}

// Pass D2: per-bucket fine scatter into colw (writes confined to the
// bucket's ~32KB region -> one block/XCD -> L2 lines merge fully).
__global__ __launch_bounds__(256) void bucket_fill_kernel(
    const unsigned long long* __restrict__ ebuf, const int* __restrict__ boff,
    const int* __restrict__ rowp, const float* __restrict__ dinv,
    unsigned int* __restrict__ colw, int n) {
  __shared__ int cur[BWID];
  int t = threadIdx.x;
  int b = blockIdx.x, node0 = b << BSH;
  for (int k = t; k < BWID; k += 256) {
    int node = node0 + k;
    cur[k] = (node < n) ? rowp[node] : 0;
  }
  __syncthreads();
  int ebeg = boff[b], eend = boff[b + 1];
  for (int i = ebeg + t; i < eend; i += 256) {
    unsigned long long p = ebuf[i];
    int d = (int)(p >> 32);
    int s = (int)(unsigned int)p;
    float w = dinv[s] * dinv[d];
    unsigned int wq = (unsigned int)(w * 32767.0f + 0.5f);
    int pos = atomicAdd(&cur[d - node0], 1);
    colw[pos] = ((unsigned int)s << 15) | wq;
  }
}

// W fp32 [k][n] -> Wt bf16 [n][k]  (128x128), 3 weights in one launch
__global__ __launch_bounds__(256) void wprep_kernel(
    const float* __restrict__ W0, const float* __restrict__ W1,
    const float* __restrict__ W2, unsigned short* __restrict__ Wt0,
    unsigned short* __restrict__ Wt1, unsigned short* __restrict__ Wt2) {
  int which = blockIdx.x >> 6;
  int i = (blockIdx.x & 63) * 256 + threadIdx.x;
  int nn = i >> 7, k = i & 127;
  const float* W = which == 0 ? W0 : (which == 1 ? W1 : W2);
  unsigned short* Wt = which == 0 ? Wt0 : (which == 1 ? Wt1 : Wt2);
  Wt[nn * 128 + k] = f2bf(W[k * 128 + nn]);
}

// ---------------- Aggregate (XCD-sharded feature halves) ----------------
// Each wave processes ONE (node, half) pair: 64 of the 128 features.
// Half selection is derived from blockIdx%8 (round-robin XCD dispatch):
// XCDs 0-3 -> bytes [0,128) of every row, XCDs 4-7 -> bytes [128,256).
// Per-XCD unique table footprint halves -> compulsory HBM fetch halves.
// Octet-split gathers: lanes (o*8..o*8+7) handle edge j+..+o, 16B/lane
// -> 8 edges per VMEM instr; 32-edge step issues 4 independent gathers.
// Lanes >= cnt carry pk=0 (row 0, weight 0): body runs unconditionally.
__global__ __launch_bounds__(256) void aggregate_kernel(
    const unsigned short* __restrict__ hWb, const int* __restrict__ row_ptr,
    const unsigned int* __restrict__ colw, const float* __restrict__ dinv,
    const float* __restrict__ bias, const float* __restrict__ resid,
    float* __restrict__ out, int n) {
  int bi = blockIdx.x;
  int h = (bi >> 2) & 1;                    // bit2 of (bi%8): XCD 0-3 vs 4-7
  int ng = (bi >> 3) * 4 + (bi & 3);        // node-group, bijective per half
  int node = ng * 4 + (threadIdx.x >> 6);
  int lane = threadIdx.x & 63;
  if (node >= n) return;  // wave-uniform
  int o = lane >> 3;      // octet: which edge of the 8-pack
  int s = lane & 7;
  int lb = s * 16 + h * 128;  // byte offset within a 256B row
  int fs = s * 8 + o;         // feature owned in the epilogue (within half)
  const char* hWbc = (const char*)hWb;
  int beg = row_ptr[node], end = row_ptr[node + 1];
  const float WQI = 1.0f / 32767.0f;

  // hoisted independent loads: self word, bias, resid, dinv
  float selfv = bf2f(*(const unsigned short*)(
      hWbc + (size_t)node * 256 + (unsigned)(lb + o * 2)));
  float bvv = bias[h * 64 + fs];
  size_t oidx = (size_t)node * 128 + (unsigned)(h * 64 + fs);
  float rvv = 0.0f;
  if (resid != nullptr) rvv = __builtin_nontemporal_load(&resid[oidx]);
  float di = dinv[node];

  f32x2 acc2[4];
  #pragma unroll
  for (int m = 0; m < 4; ++m) acc2[m] = (f32x2){0.0f, 0.0f};

  for (int cbeg = beg; cbeg < end; cbeg += 64) {
    int cnt = end - cbeg; if (cnt > 64) cnt = 64;
    unsigned int pk = 0;                 // lanes >= cnt: row 0, weight 0
    if (lane < cnt) pk = __builtin_nontemporal_load(&colw[cbeg + lane]);
    unsigned int bo = (pk >> 15) << 8;   // row byte offset (s * 256)
    float wv = (float)(pk & 0x7fffu) * WQI;
    for (int j = 0; j < cnt; j += 32) {
      unsigned int b0 = (unsigned int)__shfl((int)bo, j + 0 + o, 64);
      unsigned int b1 = (unsigned int)__shfl((int)bo, j + 8 + o, 64);
      unsigned int b2 = (unsigned int)__shfl((int)bo, j + 16 + o, 64);
      unsigned int b3 = (unsigned int)__shfl((int)bo, j + 24 + o, 64);
      float w0 = __shfl(wv, j + 0 + o, 64);
      float w1 = __shfl(wv, j + 8 + o, 64);
      float w2 = __shfl(wv, j + 16 + o, 64);
      float w3 = __shfl(wv, j + 24 + o, 64);
      // 4 independent gathers, issued back-to-back
      i32x4 p0 = *(const i32x4*)(hWbc + (b0 + (unsigned int)lb));
      i32x4 p1 = *(const i32x4*)(hWbc + (b1 + (unsigned int)lb));
      i32x4 p2 = *(const i32x4*)(hWbc + (b2 + (unsigned int)lb));
      i32x4 p3 = *(const i32x4*)(hWbc + (b3 + (unsigned int)lb));
      #pragma unroll
      for (int m = 0; m < 4; ++m) {
        int u = p0[m];
        f32x2 v;
        v.x = __int_as_float(u << 16);
        v.y = __int_as_float((int)(u & 0xffff0000));
        acc2[m] += (f32x2){w0, w0} * v;
      }
      #pragma unroll
      for (int m = 0; m < 4; ++m) {
        int u = p1[m];
        f32x2 v;
        v.x = __int_as_float(u << 16);
        v.y = __int_as_float((int)(u & 0xffff0000));
        acc2[m] += (f32x2){w1, w1} * v;
      }
      #pragma unroll
      for (int m = 0; m < 4; ++m) {
        int u = p2[m];
        f32x2 v;
        v.x = __int_as_float(u << 16);
        v.y = __int_as_float((int)(u & 0xffff0000));
        acc2[m] += (f32x2){w2, w2} * v;
      }
      #pragma unroll
      for (int m = 0; m < 4; ++m) {
        int u = p3[m];
        f32x2 v;
        v.x = __int_as_float(u << 16);
        v.y = __int_as_float((int)(u & 0xffff0000));
        acc2[m] += (f32x2){w3, w3} * v;
      }
    }
  }

  // reduce across the 8 octets: all lanes end with full sums for their
  // 8 features [s*8, s*8+8) of this half
  #pragma unroll
  for (int m = 0; m < 4; ++m) {
    acc2[m].x += __shfl_xor(acc2[m].x, 8, 64);
    acc2[m].x += __shfl_xor(acc2[m].x, 16, 64);
    acc2[m].x += __shfl_xor(acc2[m].x, 32, 64);
    acc2[m].y += __shfl_xor(acc2[m].y, 8, 64);
    acc2[m].y += __shfl_xor(acc2[m].y, 16, 64);
    acc2[m].y += __shfl_xor(acc2[m].y, 32, 64);
  }

  // epilogue, all 64 lanes active: octet o owns feature s*8 + o
  float sv = 0.0f;
  int mo = o >> 1;
  #pragma unroll
  for (int k = 0; k < 4; ++k) {
    if (mo == k) sv = (o & 1) ? acc2[k].y : acc2[k].x;
  }
  float a = sv + di * di * selfv + bvv + rvv;
  float r = a > 0.0f ? a : expm1f(a);
  __builtin_nontemporal_store(r, &out[oidx]);
}

extern "C" void kernel_launch(void* const* d_in, const int* in_sizes, int n_in,
                              void* d_out, int out_size, void* d_ws, size_t ws_size,
                              hipStream_t stream) {
  const float* x  = (const float*)d_in[0];
  const int* eidx = (const int*)d_in[1];
  const float* W0 = (const float*)d_in[2];
  const float* b0 = (const float*)d_in[3];
  const float* W1 = (const float*)d_in[4];
  const float* b1 = (const float*)d_in[5];
  const float* W2 = (const float*)d_in[6];
  const float* b2 = (const float*)d_in[7];
  float* outp = (float*)d_out;

  const int N = in_sizes[0] / NFEAT;   // 100000
  const int E = in_sizes[1] / 2;       // 1600000 (divisible by 4)
  const int* src = eidx;
  const int* dst = eidx + E;
  const int NBUC = (N + BWID - 1) >> BSH;  // 196
  const int e4 = E / 4;

  // workspace layout (all chunk sizes 1KB-multiples)
  const size_t S1 = 401408;                   // > (N+1)*4
  const size_t SBK = 1024;                    // > (NBUC+1)*4
  const size_t SW = 32768;                    // 128*128*2
  const size_t SE = (size_t)E * 4;            // 6.4 MB packed edges
  const size_t SEB = (size_t)E * 8;           // 12.8 MB bucketed (dst,src)
  const size_t SH = (size_t)N * NFEAT * 2;    // 25.6 MB bf16 features
  const size_t SF = (size_t)N * NFEAT * 4;    // 51.2 MB fp32 features
  char* p = (char*)d_ws;
  float* dinv   = (float*)p;            p += S1;
  int*   rowp   = (int*)p;              p += S1;
  int*   bcnt   = (int*)p;              p += SBK;
  int*   boff   = (int*)p;              p += SBK;
  int*   gcur   = (int*)p;              p += SBK;
  unsigned short* Wt0 = (unsigned short*)p;  p += SW;
  unsigned short* Wt1 = (unsigned short*)p;  p += SW;
  unsigned short* Wt2 = (unsigned short*)p;  p += SW;
  unsigned int* colw = (unsigned int*)p; p += SE;
  unsigned long long* ebuf = (unsigned long long*)p; p += SEB;
  unsigned short* hWb = (unsigned short*)p;  p += SH;
  float* hA     = (float*)p;            p += SF;
  float* hB     = (float*)p;            p += SF;

  int gemm_blocks = (N + 63) / 64;        // 1563
  int cbk = (e4 + 1023) / 1024;           // 391 (4096 edges/block)
  int NB = (N + 3) / 4;                   // node-groups of 4 nodes
  NB = (NB + 3) & ~3;                     // pad: bijection needs 4 | NB
  int agg_blocks = 2 * NB;                // x2 feature halves (50000)

  // ---- prep + fused {gemm0, Pass A} ----
  wprep_kernel<<<192, 256, 0, stream>>>(W0, W1, W2, Wt0, Wt1, Wt2);
  hipMemsetAsync(bcnt, 0, (size_t)NBUC * 4, stream);
  fused_g0_hist_kernel<<<gemm_blocks + cbk, 256, 0, stream>>>(
      x, Wt0, hWb, N, gemm_blocks, (const int4*)dst, bcnt, e4, NBUC);

  // ---- bucketed CSR build ----
  scan_buckets_kernel<<<1, 256, 0, stream>>>(bcnt, boff, gcur, rowp,
                                             NBUC, N, E);
  bucket_scatter_kernel<<<cbk, 256, 0, stream>>>(
      (const int4*)src, (const int4*)dst, gcur, ebuf, e4);
  bucket_deg_kernel<<<NBUC, 256, 0, stream>>>(ebuf, boff, rowp, dinv, N);
  bucket_fill_kernel<<<NBUC, 256, 0, stream>>>(ebuf, boff, rowp, dinv,
                                               colw, N);

  // ---- layer 0 aggregate (gemm0 already done) ----
  aggregate_kernel<<<agg_blocks, 256, 0, stream>>>(hWb, rowp, colw, dinv,
                                                   b0, nullptr, hA, N);
  // ---- layer 1 ----
  gemm_mfma_kernel<<<gemm_blocks, 256, 0, stream>>>(hA, Wt1, hWb, N);
  aggregate_kernel<<<agg_blocks, 256, 0, stream>>>(hWb, rowp, colw, dinv,
                                                   b1, hA, hB, N);
  // ---- layer 2, write d_out ----
  gemm_mfma_kernel<<<gemm_blocks, 256, 0, stream>>>(hB, Wt2, hWb, N);
  aggregate_kernel<<<agg_blocks, 256, 0, stream>>>(hWb, rowp, colw, dinv,
                                                   b2, hB, outp, N);
}

// Round 5
// 455.944 us; speedup vs baseline: 1.2024x; 1.2024x over previous
//
#include <hip/hip_runtime.h>
#include <math.h>

// GCN: h = elu(D^-1/2 (A+I) D^-1/2 (h W) + b [+ resid])
// N=100000 nodes, E=1600000 edges, 128 features per layer.
//
// R12 == R11 resubmitted (round 4 bench was an infra failure: "MI355X
// container failed twice", no compile/test/profile output; source
// re-audited, no OOB or crash path found).
//
// R11 changes vs R10: revert aggregate to R9 structure (R10's XCD shard
// halved gather bytes exactly as predicted, 213.8->187MB, but doubled
// per-edge VALU: 37->66us of VALU cycles -> 47% slower. Aggregate is
// NOT byte-bound; dur ~= VALU + ~33us latency floor).
// New in R11: h-chain (hA/hB) stored as f16 instead of f32.
//  - f16 mantissa (10b) is 8x more accurate than the bf16 gather table,
//    range trivially OK -> absmax unchanged.
//  - Saves ~150MB of pure streaming traffic (agg writes, gemm reads,
//    resid reads all halve) with ZERO added VALU in the edge loop.
//  - GEMM layers 1/2 use mfma_f32_16x16x32_f16 directly on f16 input
//    (same rate as bf16), dropping 32 f2bf per thread in staging.
//  - Aggregate gains mode flag: 0=out f16, 1=+resid f16, 2=out f32
//    final layer.

#define NFEAT 128
#define LDSP 136   // LDS row pitch in shorts (128 + 8 pad)
#define BSH 9      // bucket shift: 512 nodes/bucket
#define BWID 512

typedef short short8 __attribute__((ext_vector_type(8)));
typedef unsigned short ushort8 __attribute__((ext_vector_type(8)));
typedef _Float16 half8 __attribute__((ext_vector_type(8)));
typedef float f32x4 __attribute__((ext_vector_type(4)));
typedef float f32x2 __attribute__((ext_vector_type(2)));
typedef int i32x4 __attribute__((ext_vector_type(4)));

static __device__ __forceinline__ unsigned short f2bf(float f) {
  union { float f; unsigned int u; } v; v.f = f;
  unsigned int r = v.u + 0x7fffu + ((v.u >> 16) & 1u);  // RNE (finite values)
  return (unsigned short)(r >> 16);
}
static __device__ __forceinline__ float bf2f(unsigned short b) {
  union { unsigned int u; float f; } v; v.u = ((unsigned int)b) << 16;
  return v.f;
}

// ---------------- GEMM body, fp32 input -> bf16 MFMA (layer 0) --------
static __device__ __forceinline__ void gemm_body(
    int gblk, const float* __restrict__ h, const unsigned short* __restrict__ Wt,
    unsigned short* __restrict__ out, int n, unsigned short* lds) {
  int t = threadIdx.x;
  int block0 = gblk * 64;

  const f32x4* h4 = (const f32x4*)h;
  #pragma unroll
  for (int i = 0; i < 8; ++i) {
    int idx = t + 256 * i;          // 0..2047
    int r = idx >> 5, c = idx & 31; // row, float4-col
    int grow = block0 + r; if (grow >= n) grow = n - 1;
    f32x4 v = __builtin_nontemporal_load(&h4[(size_t)grow * 32 + c]);
    ushort4 b;
    b.x = f2bf(v.x); b.y = f2bf(v.y); b.z = f2bf(v.z); b.w = f2bf(v.w);
    *(ushort4*)&lds[r * LDSP + c * 4] = b;
  }
  __syncthreads();

  int lane = t & 63, wave = t >> 6;
  int row16 = lane & 15;
  int kgrp = lane >> 4;

  short8 afrag[4];
  #pragma unroll
  for (int ks = 0; ks < 4; ++ks)
    afrag[ks] =
        *(const short8*)&lds[(wave * 16 + row16) * LDSP + ks * 32 + kgrp * 8];

  f32x4 acc[8];
  #pragma unroll
  for (int ct = 0; ct < 8; ++ct) {
    acc[ct] = (f32x4){0.0f, 0.0f, 0.0f, 0.0f};
    const short8* wrow =
        (const short8*)(Wt + (size_t)(ct * 16 + row16) * NFEAT);
    #pragma unroll
    for (int ks = 0; ks < 4; ++ks) {
      acc[ct] = __builtin_amdgcn_mfma_f32_16x16x32_bf16(
          wrow[ks * 4 + kgrp], afrag[ks], acc[ct], 0, 0, 0);
    }
  }

  int orow = block0 + wave * 16 + row16;
  if (orow < n) {
    unsigned short* op = out + (size_t)orow * NFEAT + kgrp * 4;
    #pragma unroll
    for (int ct = 0; ct < 8; ++ct) {
      ushort4 o;
      o.x = f2bf(acc[ct][0]); o.y = f2bf(acc[ct][1]);
      o.z = f2bf(acc[ct][2]); o.w = f2bf(acc[ct][3]);
      *(ushort4*)(op + ct * 16) = o;
    }
  }
}

// ---------------- GEMM body, f16 input -> f16 MFMA (layers 1,2) -------
__global__ __launch_bounds__(256) void gemm_f16_kernel(
    const unsigned short* __restrict__ h16,  // f16 bits [n][128]
    const unsigned short* __restrict__ Wt,   // f16 bits [128][128] (n-major)
    unsigned short* __restrict__ out, int n) {
  __shared__ int lds_i[64 * LDSP / 2];
  unsigned short* lds = (unsigned short*)lds_i;
  int t = threadIdx.x;
  int block0 = blockIdx.x * 64;

  const ushort8* h8 = (const ushort8*)h16;
  #pragma unroll
  for (int i = 0; i < 4; ++i) {
    int idx = t + 256 * i;          // 0..1023
    int r = idx >> 4, c = idx & 15; // row, 8-elem col
    int grow = block0 + r; if (grow >= n) grow = n - 1;
    ushort8 v = __builtin_nontemporal_load(&h8[(size_t)grow * 16 + c]);
    *(ushort8*)&lds[r * LDSP + c * 8] = v;
  }
  __syncthreads();

  int lane = t & 63, wave = t >> 6;
  int row16 = lane & 15;
  int kgrp = lane >> 4;

  half8 afrag[4];
  #pragma unroll
  for (int ks = 0; ks < 4; ++ks)
    afrag[ks] =
        *(const half8*)&lds[(wave * 16 + row16) * LDSP + ks * 32 + kgrp * 8];

  f32x4 acc[8];
  #pragma unroll
  for (int ct = 0; ct < 8; ++ct) {
    acc[ct] = (f32x4){0.0f, 0.0f, 0.0f, 0.0f};
    const half8* wrow =
        (const half8*)(Wt + (size_t)(ct * 16 + row16) * NFEAT);
    #pragma unroll
    for (int ks = 0; ks < 4; ++ks) {
      acc[ct] = __builtin_amdgcn_mfma_f32_16x16x32_f16(
          wrow[ks * 4 + kgrp], afrag[ks], acc[ct], 0, 0, 0);
    }
  }

  int orow = block0 + wave * 16 + row16;
  if (orow < n) {
    unsigned short* op = out + (size_t)orow * NFEAT + kgrp * 4;
    #pragma unroll
    for (int ct = 0; ct < 8; ++ct) {
      ushort4 o;
      o.x = f2bf(acc[ct][0]); o.y = f2bf(acc[ct][1]);
      o.z = f2bf(acc[ct][2]); o.w = f2bf(acc[ct][3]);
      *(ushort4*)(op + ct * 16) = o;
    }
  }
}

// gemm0 fused with Pass A (bucket histogram) — independent work.
__global__ __launch_bounds__(256) void fused_g0_hist_kernel(
    const float* __restrict__ x, const unsigned short* __restrict__ Wt0,
    unsigned short* __restrict__ hWb, int n, int gb,
    const int4* __restrict__ dst4, int* __restrict__ bcnt, int e4, int nbuc) {
  __shared__ int lds_i[64 * LDSP / 2];
  int t = threadIdx.x;
  if ((int)blockIdx.x < gb) {
    gemm_body(blockIdx.x, x, Wt0, hWb, n, (unsigned short*)lds_i);
  } else {
    int* hist = lds_i;
    hist[t] = 0;
    __syncthreads();
    int base = ((int)blockIdx.x - gb) * 1024;
    #pragma unroll
    for (int i = 0; i < 4; ++i) {
      int idx = base + t + 256 * i;
      if (idx < e4) {
        int4 d = dst4[idx];
        atomicAdd(&hist[d.x >> BSH], 1);
        atomicAdd(&hist[d.y >> BSH], 1);
        atomicAdd(&hist[d.z >> BSH], 1);
        atomicAdd(&hist[d.w >> BSH], 1);
      }
    }
    __syncthreads();
    int h = hist[t];
    if (t < nbuc && h) atomicAdd(&bcnt[t], h);
  }
}

// Pass B: exclusive scan of bucket counts (nbuc <= 256), init gcur, rowp[n]=E
__global__ __launch_bounds__(256) void scan_buckets_kernel(
    const int* __restrict__ bcnt, int* __restrict__ boff,
    int* __restrict__ gcur, int* __restrict__ rowp, int nbuc, int n, int e) {
  __shared__ int wsum[4];
  int t = threadIdx.x, lane = t & 63, wid = t >> 6;
  int v = (t < nbuc) ? bcnt[t] : 0;
  int s = v;
  #pragma unroll
  for (int off = 1; off < 64; off <<= 1) {
    int u = __shfl_up(s, off, 64);
    if (lane >= off) s += u;
  }
  if (lane == 63) wsum[wid] = s;
  __syncthreads();
  int add = 0;
  for (int w = 0; w < wid; ++w) add += wsum[w];
  int incl = add + s;
  if (t < nbuc) { boff[t] = incl - v; gcur[t] = incl - v; }
  if (t == nbuc - 1) boff[nbuc] = incl;  // == E
  if (t == 0) rowp[n] = e;
}

// Pass C: scatter (dst,src) u64 into bucket-major ebuf, block-chunked.
__global__ __launch_bounds__(256) void bucket_scatter_kernel(
    const int4* __restrict__ src4, const int4* __restrict__ dst4,
    int* __restrict__ gcur, unsigned long long* __restrict__ ebuf, int e4) {
  __shared__ int hist[256];
  __shared__ int cbase[256];
  __shared__ int cur[256];
  int t = threadIdx.x;
  hist[t] = 0; cur[t] = 0;
  __syncthreads();
  int base = blockIdx.x * 1024;
  int4 dv[4], sv[4];
  bool val[4];
  #pragma unroll
  for (int i = 0; i < 4; ++i) {
    int idx = base + t + 256 * i;
    val[i] = idx < e4;
    if (val[i]) {
      dv[i] = dst4[idx];
      sv[i] = src4[idx];
      atomicAdd(&hist[dv[i].x >> BSH], 1);
      atomicAdd(&hist[dv[i].y >> BSH], 1);
      atomicAdd(&hist[dv[i].z >> BSH], 1);
      atomicAdd(&hist[dv[i].w >> BSH], 1);
    }
  }
  __syncthreads();
  int h = hist[t];
  if (h) cbase[t] = atomicAdd(&gcur[t], h);  // hist[t]==0 for t>=nbuc
  __syncthreads();
  #pragma unroll
  for (int i = 0; i < 4; ++i) {
    if (val[i]) {
      int d, s, b, p;
      d = dv[i].x; s = sv[i].x; b = d >> BSH;
      p = cbase[b] + atomicAdd(&cur[b], 1);
      ebuf[p] = ((unsigned long long)(unsigned)d << 32) | (unsigned)s;
      d = dv[i].y; s = sv[i].y; b = d >> BSH;
      p = cbase[b] + atomicAdd(&cur[b], 1);
      ebuf[p] = ((unsigned long long)(unsigned)d << 32) | (unsigned)s;
      d = dv[i].z; s = sv[i].z; b = d >> BSH;
      p = cbase[b] + atomicAdd(&cur[b], 1);
      ebuf[p] = ((unsigned long long)(unsigned)d << 32) | (unsigned)s;
      d = dv[i].w; s = sv[i].w; b = d >> BSH;
      p = cbase[b] + atomicAdd(&cur[b], 1);
      ebuf[p] = ((unsigned long long)(unsigned)d << 32) | (unsigned)s;
    }
  }
}

// Pass D1: per-bucket degree hist (LDS) + local scan -> rowp, dinv.
__global__ __launch_bounds__(256) void bucket_deg_kernel(
    const unsigned long long* __restrict__ ebuf, const int* __restrict__ boff,
    int* __restrict__ rowp, float* __restrict__ dinv, int n) {
  __shared__ int deg[BWID];
  __shared__ int wsum[4];
  int t = threadIdx.x;
  int b = blockIdx.x, node0 = b << BSH;
  deg[t] = 0; deg[t + 256] = 0;
  __syncthreads();
  int ebeg = boff[b], eend = boff[b + 1];
  for (int i = ebeg + t; i < eend; i += 256) {
    int d = (int)(ebuf[i] >> 32);
    atomicAdd(&deg[d - node0], 1);
  }
  __syncthreads();
  int d0 = deg[2 * t], d1 = deg[2 * t + 1];
  int s = d0 + d1;
  int lane = t & 63, wid = t >> 6;
  int sc = s;
  #pragma unroll
  for (int off = 1; off < 64; off <<= 1) {
    int u = __shfl_up(sc, off, 64);
    if (lane >= off) sc += u;
  }
  if (lane == 63) wsum[wid] = sc;
  __syncthreads();
  int add = 0;
  for (int w = 0; w < wid; ++w) add += wsum[w];
  int excl = ebeg + add + sc - s;  // rowp of node 2t in this bucket
  int node = node0 + 2 * t;
  if (node < n) {
    rowp[node] = excl;
    dinv[node] = rsqrtf(1.0f + (float)d0);
  }
  if (node + 1 < n) {
    rowp[node + 1] = excl + d0;
    dinv[node + 1] = rsqrtf(1.0f + (float)d1);
  }
}

// Pass D2: per-bucket fine scatter into colw (writes confined to the
// bucket's ~32KB region -> one block/XCD -> L2 lines merge fully).
__global__ __launch_bounds__(256) void bucket_fill_kernel(
    const unsigned long long* __restrict__ ebuf, const int* __restrict__ boff,
    const int* __restrict__ rowp, const float* __restrict__ dinv,
    unsigned int* __restrict__ colw, int n) {
  __shared__ int cur[BWID];
  int t = threadIdx.x;
  int b = blockIdx.x, node0 = b << BSH;
  for (int k = t; k < BWID; k += 256) {
    int node = node0 + k;
    cur[k] = (node < n) ? rowp[node] : 0;
  }
  __syncthreads();
  int ebeg = boff[b], eend = boff[b + 1];
  for (int i = ebeg + t; i < eend; i += 256) {
    unsigned long long p = ebuf[i];
    int d = (int)(p >> 32);
    int s = (int)(unsigned int)p;
    float w = dinv[s] * dinv[d];
    unsigned int wq = (unsigned int)(w * 32767.0f + 0.5f);
    int pos = atomicAdd(&cur[d - node0], 1);
    colw[pos] = ((unsigned int)s << 15) | wq;
  }
}

// W fp32 [k][n] -> Wt0 bf16 [n][k]; Wt1/Wt2 f16 [n][k]
__global__ __launch_bounds__(256) void wprep_kernel(
    const float* __restrict__ W0, const float* __restrict__ W1,
    const float* __restrict__ W2, unsigned short* __restrict__ Wt0,
    unsigned short* __restrict__ Wt1, unsigned short* __restrict__ Wt2) {
  int which = blockIdx.x >> 6;
  int i = (blockIdx.x & 63) * 256 + threadIdx.x;
  int nn = i >> 7, k = i & 127;
  const float* W = which == 0 ? W0 : (which == 1 ? W1 : W2);
  float v = W[k * 128 + nn];
  if (which == 0) {
    Wt0[nn * 128 + k] = f2bf(v);
  } else {
    union { _Float16 h; unsigned short u; } c;
    c.h = (_Float16)v;
    (which == 1 ? Wt1 : Wt2)[nn * 128 + k] = c.u;
  }
}

// ---------------- Aggregate (R9 structure + f16 h-chain I/O) ----------
// One wave per node, quarter-split gathers: lanes (q*16..q*16+15) handle
// edge j+4k+q; each lane loads 16B (dwordx4) of a row. Inner loop steps
// 16 edges issuing 4 independent gathers back-to-back.
// mode 0: out f16, no resid. mode 1: out f16, resid f16. mode 2: out
// f32, resid f16 (final layer).
__global__ __launch_bounds__(256) void aggregate_kernel(
    const unsigned short* __restrict__ hWb, const int* __restrict__ row_ptr,
    const unsigned int* __restrict__ colw, const float* __restrict__ dinv,
    const float* __restrict__ bias, const unsigned int* __restrict__ resid16,
    void* __restrict__ out, int n, int mode) {
  int node = blockIdx.x * 4 + (threadIdx.x >> 6);
  int lane = threadIdx.x & 63;
  if (node >= n) return;  // wave-uniform
  int q = lane >> 4;      // quarter: which edge of the 4-pack
  int l15 = lane & 15;
  int lb = l15 * 16;      // byte offset within a 256B row
  const char* hWbc = (const char*)hWb;
  int beg = row_ptr[node], end = row_ptr[node + 1];
  const float WQI = 1.0f / 32767.0f;

  // hoisted independent loads: self row word, bias, resid, dinv
  unsigned int su =
      *(const unsigned int*)(hWbc + (size_t)node * 256 + (unsigned)(lb + q * 4));
  f32x2 bv = ((const f32x2*)bias)[l15 * 4 + q];
  size_t oidx = (size_t)node * 64 + (unsigned)(l15 * 4 + q);
  float rx = 0.0f, ry = 0.0f;
  if (mode >= 1) {
    unsigned int rv = __builtin_nontemporal_load(&resid16[oidx]);
    union { unsigned short u; _Float16 h; } c0, c1;
    c0.u = (unsigned short)(rv & 0xffffu);
    c1.u = (unsigned short)(rv >> 16);
    rx = (float)c0.h; ry = (float)c1.h;
  }
  float di = dinv[node];

  f32x2 acc2[4];
  #pragma unroll
  for (int m = 0; m < 4; ++m) acc2[m] = (f32x2){0.0f, 0.0f};

  for (int cbeg = beg; cbeg < end; cbeg += 64) {
    int cnt = end - cbeg; if (cnt > 64) cnt = 64;
    unsigned int pk = 0;                 // lanes >= cnt: row 0, weight 0
    if (lane < cnt) pk = __builtin_nontemporal_load(&colw[cbeg + lane]);
    unsigned int bo = (pk >> 15) << 8;   // row byte offset (s * 256)
    float wv = (float)(pk & 0x7fffu) * WQI;
    for (int j = 0; j < cnt; j += 16) {
      unsigned int b0 = (unsigned int)__shfl((int)bo, j + 0 + q, 64);
      unsigned int b1 = (unsigned int)__shfl((int)bo, j + 4 + q, 64);
      unsigned int b2 = (unsigned int)__shfl((int)bo, j + 8 + q, 64);
      unsigned int b3 = (unsigned int)__shfl((int)bo, j + 12 + q, 64);
      float w0 = __shfl(wv, j + 0 + q, 64);
      float w1 = __shfl(wv, j + 4 + q, 64);
      float w2 = __shfl(wv, j + 8 + q, 64);
      float w3 = __shfl(wv, j + 12 + q, 64);
      // 4 independent gathers, issued back-to-back
      i32x4 p0 = *(const i32x4*)(hWbc + (b0 + (unsigned int)lb));
      i32x4 p1 = *(const i32x4*)(hWbc + (b1 + (unsigned int)lb));
      i32x4 p2 = *(const i32x4*)(hWbc + (b2 + (unsigned int)lb));
      i32x4 p3 = *(const i32x4*)(hWbc + (b3 + (unsigned int)lb));
      #pragma unroll
      for (int m = 0; m < 4; ++m) {
        int u = p0[m];
        f32x2 v;
        v.x = __int_as_float(u << 16);
        v.y = __int_as_float((int)(u & 0xffff0000));
        acc2[m] += (f32x2){w0, w0} * v;
      }
      #pragma unroll
      for (int m = 0; m < 4; ++m) {
        int u = p1[m];
        f32x2 v;
        v.x = __int_as_float(u << 16);
        v.y = __int_as_float((int)(u & 0xffff0000));
        acc2[m] += (f32x2){w1, w1} * v;
      }
      #pragma unroll
      for (int m = 0; m < 4; ++m) {
        int u = p2[m];
        f32x2 v;
        v.x = __int_as_float(u << 16);
        v.y = __int_as_float((int)(u & 0xffff0000));
        acc2[m] += (f32x2){w2, w2} * v;
      }
      #pragma unroll
      for (int m = 0; m < 4; ++m) {
        int u = p3[m];
        f32x2 v;
        v.x = __int_as_float(u << 16);
        v.y = __int_as_float((int)(u & 0xffff0000));
        acc2[m] += (f32x2){w3, w3} * v;
      }
    }
  }

  // reduce across the 4 quarters
  #pragma unroll
  for (int m = 0; m < 4; ++m) {
    acc2[m].x += __shfl_xor(acc2[m].x, 16, 64);
    acc2[m].x += __shfl_xor(acc2[m].x, 32, 64);
    acc2[m].y += __shfl_xor(acc2[m].y, 16, 64);
    acc2[m].y += __shfl_xor(acc2[m].y, 32, 64);
  }

  // epilogue, all 64 lanes active: quarter q owns columns 2q, 2q+1 of
  // this lane's 8-column slice
  float sx = 0.0f, sy = 0.0f;
  #pragma unroll
  for (int k = 0; k < 4; ++k) {
    if (q == k) { sx = acc2[k].x; sy = acc2[k].y; }
  }
  float dii = di * di;
  float ax = sx + dii * __int_as_float((int)(su << 16)) + bv.x + rx;
  float ay = sy + dii * __int_as_float((int)(su & 0xffff0000u)) + bv.y + ry;
  float ox = ax > 0.0f ? ax : expm1f(ax);
  float oy = ay > 0.0f ? ay : expm1f(ay);
  if (mode == 2) {
    f32x2 o; o.x = ox; o.y = oy;
    __builtin_nontemporal_store(o, &((f32x2*)out)[oidx]);
  } else {
    union { unsigned short u; _Float16 h; } c0, c1;
    c0.h = (_Float16)ox; c1.h = (_Float16)oy;
    unsigned int pk2 = ((unsigned int)c1.u << 16) | c0.u;
    __builtin_nontemporal_store(pk2, &((unsigned int*)out)[oidx]);
  }
}

extern "C" void kernel_launch(void* const* d_in, const int* in_sizes, int n_in,
                              void* d_out, int out_size, void* d_ws, size_t ws_size,
                              hipStream_t stream) {
  const float* x  = (const float*)d_in[0];
  const int* eidx = (const int*)d_in[1];
  const float* W0 = (const float*)d_in[2];
  const float* b0 = (const float*)d_in[3];
  const float* W1 = (const float*)d_in[4];
  const float* b1 = (const float*)d_in[5];
  const float* W2 = (const float*)d_in[6];
  const float* b2 = (const float*)d_in[7];
  float* outp = (float*)d_out;

  const int N = in_sizes[0] / NFEAT;   // 100000
  const int E = in_sizes[1] / 2;       // 1600000 (divisible by 4)
  const int* src = eidx;
  const int* dst = eidx + E;
  const int NBUC = (N + BWID - 1) >> BSH;  // 196
  const int e4 = E / 4;

  // workspace layout (all chunk sizes 1KB-multiples)
  const size_t S1 = 401408;                   // > (N+1)*4
  const size_t SBK = 1024;                    // > (NBUC+1)*4
  const size_t SW = 32768;                    // 128*128*2
  const size_t SE = (size_t)E * 4;            // 6.4 MB packed edges
  const size_t SEB = (size_t)E * 8;           // 12.8 MB bucketed (dst,src)
  const size_t SH = (size_t)N * NFEAT * 2;    // 25.6 MB bf16/f16 features
  char* p = (char*)d_ws;
  float* dinv   = (float*)p;            p += S1;
  int*   rowp   = (int*)p;              p += S1;
  int*   bcnt   = (int*)p;              p += SBK;
  int*   boff   = (int*)p;              p += SBK;
  int*   gcur   = (int*)p;              p += SBK;
  unsigned short* Wt0 = (unsigned short*)p;  p += SW;  // bf16
  unsigned short* Wt1 = (unsigned short*)p;  p += SW;  // f16
  unsigned short* Wt2 = (unsigned short*)p;  p += SW;  // f16
  unsigned int* colw = (unsigned int*)p; p += SE;
  unsigned long long* ebuf = (unsigned long long*)p; p += SEB;
  unsigned short* hWb = (unsigned short*)p;  p += SH;  // bf16 gather table
  unsigned short* hA  = (unsigned short*)p;  p += SH;  // f16 h
  unsigned short* hB  = (unsigned short*)p;  p += SH;  // f16 h

  int gemm_blocks = (N + 63) / 64;        // 1563
  int cbk = (e4 + 1023) / 1024;           // 391 (4096 edges/block)
  int agg_blocks = (N + 3) / 4;

  // ---- prep + fused {gemm0, Pass A} ----
  wprep_kernel<<<192, 256, 0, stream>>>(W0, W1, W2, Wt0, Wt1, Wt2);
  hipMemsetAsync(bcnt, 0, (size_t)NBUC * 4, stream);
  fused_g0_hist_kernel<<<gemm_blocks + cbk, 256, 0, stream>>>(
      x, Wt0, hWb, N, gemm_blocks, (const int4*)dst, bcnt, e4, NBUC);

  // ---- bucketed CSR build ----
  scan_buckets_kernel<<<1, 256, 0, stream>>>(bcnt, boff, gcur, rowp,
                                             NBUC, N, E);
  bucket_scatter_kernel<<<cbk, 256, 0, stream>>>(
      (const int4*)src, (const int4*)dst, gcur, ebuf, e4);
  bucket_deg_kernel<<<NBUC, 256, 0, stream>>>(ebuf, boff, rowp, dinv, N);
  bucket_fill_kernel<<<NBUC, 256, 0, stream>>>(ebuf, boff, rowp, dinv,
                                               colw, N);

  // ---- layer 0 aggregate (gemm0 already done): out hA f16 ----
  aggregate_kernel<<<agg_blocks, 256, 0, stream>>>(
      hWb, rowp, colw, dinv, b0, nullptr, hA, N, 0);
  // ---- layer 1 ----
  gemm_f16_kernel<<<gemm_blocks, 256, 0, stream>>>(hA, Wt1, hWb, N);
  aggregate_kernel<<<agg_blocks, 256, 0, stream>>>(
      hWb, rowp, colw, dinv, b1, (const unsigned int*)hA, hB, N, 1);
  // ---- layer 2, write d_out f32 ----
  gemm_f16_kernel<<<gemm_blocks, 256, 0, stream>>>(hB, Wt2, hWb, N);
  aggregate_kernel<<<agg_blocks, 256, 0, stream>>>(
      hWb, rowp, colw, dinv, b2, (const unsigned int*)hB, outp, N, 2);
}

// Round 7
// 450.931 us; speedup vs baseline: 1.2158x; 1.0111x over previous
//
#include <hip/hip_runtime.h>
#include <math.h>

// GCN: h = elu(D^-1/2 (A+I) D^-1/2 (h W) + b [+ resid])
// N=100000 nodes, E=1600000 edges, 128 features per layer.
//
// R14 == R13 with compile fix: __builtin_amdgcn_cvt_pkrtz returns
// __fp16x2 (not _Float16x2) -> replaced with scalar f2h + pack.
//
// R13 changes vs R12 (456us, agg 68.5us @ VALU 55%):
//  - Gather table hWb: bf16 -> f16. Inner loop accumulates in packed
//    f16 (v_pk_fma_f16): 1 VALU op per gathered dword instead of 3
//    (lshl+and+pk_fma). Accuracy IMPROVES: f16 quant 2^-11 vs bf16
//    2^-8 (the dominant error term); only ~4 terms/lane accumulate in
//    f16 before the cross-quarter reduce (f32).
//  - Tail predication: avg degree ~17 but the 16-edge step issued 4
//    gathers + 16 dword-FMAs unconditionally -> ~47% dead slots. cnt
//    is wave-uniform, so the tail now issues ceil(r/4) gathers under
//    uniform branches (no divergence).
//  - Weights shuffled pre-packed as half2.
//  - GEMM epilogues emit f16 (plain cvt, cheaper than the bf16 RNE).

#define NFEAT 128
#define LDSP 136   // LDS row pitch in shorts (128 + 8 pad)
#define BSH 9      // bucket shift: 512 nodes/bucket
#define BWID 512

typedef short short8 __attribute__((ext_vector_type(8)));
typedef unsigned short ushort8 __attribute__((ext_vector_type(8)));
typedef _Float16 half8 __attribute__((ext_vector_type(8)));
typedef _Float16 h16x2 __attribute__((ext_vector_type(2)));
typedef float f32x4 __attribute__((ext_vector_type(4)));
typedef float f32x2 __attribute__((ext_vector_type(2)));
typedef int i32x4 __attribute__((ext_vector_type(4)));

static __device__ __forceinline__ unsigned short f2bf(float f) {
  union { float f; unsigned int u; } v; v.f = f;
  unsigned int r = v.u + 0x7fffu + ((v.u >> 16) & 1u);  // RNE (finite values)
  return (unsigned short)(r >> 16);
}
static __device__ __forceinline__ unsigned short f2h(float f) {
  union { _Float16 h; unsigned short u; } c; c.h = (_Float16)f; return c.u;
}
static __device__ __forceinline__ h16x2 u2h2(int u) {
  union { int i; h16x2 h; } c; c.i = u; return c.h;
}

// ---------------- GEMM body, fp32 input -> bf16 MFMA, f16 out (L0) ----
static __device__ __forceinline__ void gemm_body(
    int gblk, const float* __restrict__ h, const unsigned short* __restrict__ Wt,
    unsigned short* __restrict__ out, int n, unsigned short* lds) {
  int t = threadIdx.x;
  int block0 = gblk * 64;

  const f32x4* h4 = (const f32x4*)h;
  #pragma unroll
  for (int i = 0; i < 8; ++i) {
    int idx = t + 256 * i;          // 0..2047
    int r = idx >> 5, c = idx & 31; // row, float4-col
    int grow = block0 + r; if (grow >= n) grow = n - 1;
    f32x4 v = __builtin_nontemporal_load(&h4[(size_t)grow * 32 + c]);
    ushort4 b;
    b.x = f2bf(v.x); b.y = f2bf(v.y); b.z = f2bf(v.z); b.w = f2bf(v.w);
    *(ushort4*)&lds[r * LDSP + c * 4] = b;
  }
  __syncthreads();

  int lane = t & 63, wave = t >> 6;
  int row16 = lane & 15;
  int kgrp = lane >> 4;

  short8 afrag[4];
  #pragma unroll
  for (int ks = 0; ks < 4; ++ks)
    afrag[ks] =
        *(const short8*)&lds[(wave * 16 + row16) * LDSP + ks * 32 + kgrp * 8];

  f32x4 acc[8];
  #pragma unroll
  for (int ct = 0; ct < 8; ++ct) {
    acc[ct] = (f32x4){0.0f, 0.0f, 0.0f, 0.0f};
    const short8* wrow =
        (const short8*)(Wt + (size_t)(ct * 16 + row16) * NFEAT);
    #pragma unroll
    for (int ks = 0; ks < 4; ++ks) {
      acc[ct] = __builtin_amdgcn_mfma_f32_16x16x32_bf16(
          wrow[ks * 4 + kgrp], afrag[ks], acc[ct], 0, 0, 0);
    }
  }

  int orow = block0 + wave * 16 + row16;
  if (orow < n) {
    unsigned short* op = out + (size_t)orow * NFEAT + kgrp * 4;
    #pragma unroll
    for (int ct = 0; ct < 8; ++ct) {
      ushort4 o;
      o.x = f2h(acc[ct][0]); o.y = f2h(acc[ct][1]);
      o.z = f2h(acc[ct][2]); o.w = f2h(acc[ct][3]);
      *(ushort4*)(op + ct * 16) = o;
    }
  }
}

// ---------------- GEMM, f16 input -> f16 MFMA, f16 out (L1, L2) -------
__global__ __launch_bounds__(256) void gemm_f16_kernel(
    const unsigned short* __restrict__ h16,  // f16 bits [n][128]
    const unsigned short* __restrict__ Wt,   // f16 bits [128][128] (n-major)
    unsigned short* __restrict__ out, int n) {
  __shared__ int lds_i[64 * LDSP / 2];
  unsigned short* lds = (unsigned short*)lds_i;
  int t = threadIdx.x;
  int block0 = blockIdx.x * 64;

  const ushort8* h8 = (const ushort8*)h16;
  #pragma unroll
  for (int i = 0; i < 4; ++i) {
    int idx = t + 256 * i;          // 0..1023
    int r = idx >> 4, c = idx & 15; // row, 8-elem col
    int grow = block0 + r; if (grow >= n) grow = n - 1;
    ushort8 v = __builtin_nontemporal_load(&h8[(size_t)grow * 16 + c]);
    *(ushort8*)&lds[r * LDSP + c * 8] = v;
  }
  __syncthreads();

  int lane = t & 63, wave = t >> 6;
  int row16 = lane & 15;
  int kgrp = lane >> 4;

  half8 afrag[4];
  #pragma unroll
  for (int ks = 0; ks < 4; ++ks)
    afrag[ks] =
        *(const half8*)&lds[(wave * 16 + row16) * LDSP + ks * 32 + kgrp * 8];

  f32x4 acc[8];
  #pragma unroll
  for (int ct = 0; ct < 8; ++ct) {
    acc[ct] = (f32x4){0.0f, 0.0f, 0.0f, 0.0f};
    const half8* wrow =
        (const half8*)(Wt + (size_t)(ct * 16 + row16) * NFEAT);
    #pragma unroll
    for (int ks = 0; ks < 4; ++ks) {
      acc[ct] = __builtin_amdgcn_mfma_f32_16x16x32_f16(
          wrow[ks * 4 + kgrp], afrag[ks], acc[ct], 0, 0, 0);
    }
  }

  int orow = block0 + wave * 16 + row16;
  if (orow < n) {
    unsigned short* op = out + (size_t)orow * NFEAT + kgrp * 4;
    #pragma unroll
    for (int ct = 0; ct < 8; ++ct) {
      ushort4 o;
      o.x = f2h(acc[ct][0]); o.y = f2h(acc[ct][1]);
      o.z = f2h(acc[ct][2]); o.w = f2h(acc[ct][3]);
      *(ushort4*)(op + ct * 16) = o;
    }
  }
}

// gemm0 fused with Pass A (bucket histogram) — independent work.
__global__ __launch_bounds__(256) void fused_g0_hist_kernel(
    const float* __restrict__ x, const unsigned short* __restrict__ Wt0,
    unsigned short* __restrict__ hWb, int n, int gb,
    const int4* __restrict__ dst4, int* __restrict__ bcnt, int e4, int nbuc) {
  __shared__ int lds_i[64 * LDSP / 2];
  int t = threadIdx.x;
  if ((int)blockIdx.x < gb) {
    gemm_body(blockIdx.x, x, Wt0, hWb, n, (unsigned short*)lds_i);
  } else {
    int* hist = lds_i;
    hist[t] = 0;
    __syncthreads();
    int base = ((int)blockIdx.x - gb) * 1024;
    #pragma unroll
    for (int i = 0; i < 4; ++i) {
      int idx = base + t + 256 * i;
      if (idx < e4) {
        int4 d = dst4[idx];
        atomicAdd(&hist[d.x >> BSH], 1);
        atomicAdd(&hist[d.y >> BSH], 1);
        atomicAdd(&hist[d.z >> BSH], 1);
        atomicAdd(&hist[d.w >> BSH], 1);
      }
    }
    __syncthreads();
    int h = hist[t];
    if (t < nbuc && h) atomicAdd(&bcnt[t], h);
  }
}

// Pass B: exclusive scan of bucket counts (nbuc <= 256), init gcur, rowp[n]=E
__global__ __launch_bounds__(256) void scan_buckets_kernel(
    const int* __restrict__ bcnt, int* __restrict__ boff,
    int* __restrict__ gcur, int* __restrict__ rowp, int nbuc, int n, int e) {
  __shared__ int wsum[4];
  int t = threadIdx.x, lane = t & 63, wid = t >> 6;
  int v = (t < nbuc) ? bcnt[t] : 0;
  int s = v;
  #pragma unroll
  for (int off = 1; off < 64; off <<= 1) {
    int u = __shfl_up(s, off, 64);
    if (lane >= off) s += u;
  }
  if (lane == 63) wsum[wid] = s;
  __syncthreads();
  int add = 0;
  for (int w = 0; w < wid; ++w) add += wsum[w];
  int incl = add + s;
  if (t < nbuc) { boff[t] = incl - v; gcur[t] = incl - v; }
  if (t == nbuc - 1) boff[nbuc] = incl;  // == E
  if (t == 0) rowp[n] = e;
}

// Pass C: scatter (dst,src) u64 into bucket-major ebuf, block-chunked.
__global__ __launch_bounds__(256) void bucket_scatter_kernel(
    const int4* __restrict__ src4, const int4* __restrict__ dst4,
    int* __restrict__ gcur, unsigned long long* __restrict__ ebuf, int e4) {
  __shared__ int hist[256];
  __shared__ int cbase[256];
  __shared__ int cur[256];
  int t = threadIdx.x;
  hist[t] = 0; cur[t] = 0;
  __syncthreads();
  int base = blockIdx.x * 1024;
  int4 dv[4], sv[4];
  bool val[4];
  #pragma unroll
  for (int i = 0; i < 4; ++i) {
    int idx = base + t + 256 * i;
    val[i] = idx < e4;
    if (val[i]) {
      dv[i] = dst4[idx];
      sv[i] = src4[idx];
      atomicAdd(&hist[dv[i].x >> BSH], 1);
      atomicAdd(&hist[dv[i].y >> BSH], 1);
      atomicAdd(&hist[dv[i].z >> BSH], 1);
      atomicAdd(&hist[dv[i].w >> BSH], 1);
    }
  }
  __syncthreads();
  int h = hist[t];
  if (h) cbase[t] = atomicAdd(&gcur[t], h);  // hist[t]==0 for t>=nbuc
  __syncthreads();
  #pragma unroll
  for (int i = 0; i < 4; ++i) {
    if (val[i]) {
      int d, s, b, p;
      d = dv[i].x; s = sv[i].x; b = d >> BSH;
      p = cbase[b] + atomicAdd(&cur[b], 1);
      ebuf[p] = ((unsigned long long)(unsigned)d << 32) | (unsigned)s;
      d = dv[i].y; s = sv[i].y; b = d >> BSH;
      p = cbase[b] + atomicAdd(&cur[b], 1);
      ebuf[p] = ((unsigned long long)(unsigned)d << 32) | (unsigned)s;
      d = dv[i].z; s = sv[i].z; b = d >> BSH;
      p = cbase[b] + atomicAdd(&cur[b], 1);
      ebuf[p] = ((unsigned long long)(unsigned)d << 32) | (unsigned)s;
      d = dv[i].w; s = sv[i].w; b = d >> BSH;
      p = cbase[b] + atomicAdd(&cur[b], 1);
      ebuf[p] = ((unsigned long long)(unsigned)d << 32) | (unsigned)s;
    }
  }
}

// Pass D1: per-bucket degree hist (LDS) + local scan -> rowp, dinv.
__global__ __launch_bounds__(256) void bucket_deg_kernel(
    const unsigned long long* __restrict__ ebuf, const int* __restrict__ boff,
    int* __restrict__ rowp, float* __restrict__ dinv, int n) {
  __shared__ int deg[BWID];
  __shared__ int wsum[4];
  int t = threadIdx.x;
  int b = blockIdx.x, node0 = b << BSH;
  deg[t] = 0; deg[t + 256] = 0;
  __syncthreads();
  int ebeg = boff[b], eend = boff[b + 1];
  for (int i = ebeg + t; i < eend; i += 256) {
    int d = (int)(ebuf[i] >> 32);
    atomicAdd(&deg[d - node0], 1);
  }
  __syncthreads();
  int d0 = deg[2 * t], d1 = deg[2 * t + 1];
  int s = d0 + d1;
  int lane = t & 63, wid = t >> 6;
  int sc = s;
  #pragma unroll
  for (int off = 1; off < 64; off <<= 1) {
    int u = __shfl_up(sc, off, 64);
    if (lane >= off) sc += u;
  }
  if (lane == 63) wsum[wid] = sc;
  __syncthreads();
  int add = 0;
  for (int w = 0; w < wid; ++w) add += wsum[w];
  int excl = ebeg + add + sc - s;  // rowp of node 2t in this bucket
  int node = node0 + 2 * t;
  if (node < n) {
    rowp[node] = excl;
    dinv[node] = rsqrtf(1.0f + (float)d0);
  }
  if (node + 1 < n) {
    rowp[node + 1] = excl + d0;
    dinv[node + 1] = rsqrtf(1.0f + (float)d1);
  }
}

// Pass D2: per-bucket fine scatter into colw (writes confined to the
// bucket's ~32KB region -> one block/XCD -> L2 lines merge fully).
__global__ __launch_bounds__(256) void bucket_fill_kernel(
    const unsigned long long* __restrict__ ebuf, const int* __restrict__ boff,
    const int* __restrict__ rowp, const float* __restrict__ dinv,
    unsigned int* __restrict__ colw, int n) {
  __shared__ int cur[BWID];
  int t = threadIdx.x;
  int b = blockIdx.x, node0 = b << BSH;
  for (int k = t; k < BWID; k += 256) {
    int node = node0 + k;
    cur[k] = (node < n) ? rowp[node] : 0;
  }
  __syncthreads();
  int ebeg = boff[b], eend = boff[b + 1];
  for (int i = ebeg + t; i < eend; i += 256) {
    unsigned long long p = ebuf[i];
    int d = (int)(p >> 32);
    int s = (int)(unsigned int)p;
    float w = dinv[s] * dinv[d];
    unsigned int wq = (unsigned int)(w * 32767.0f + 0.5f);
    int pos = atomicAdd(&cur[d - node0], 1);
    colw[pos] = ((unsigned int)s << 15) | wq;
  }
}

// W fp32 [k][n] -> Wt0 bf16 [n][k]; Wt1/Wt2 f16 [n][k]
__global__ __launch_bounds__(256) void wprep_kernel(
    const float* __restrict__ W0, const float* __restrict__ W1,
    const float* __restrict__ W2, unsigned short* __restrict__ Wt0,
    unsigned short* __restrict__ Wt1, unsigned short* __restrict__ Wt2) {
  int which = blockIdx.x >> 6;
  int i = (blockIdx.x & 63) * 256 + threadIdx.x;
  int nn = i >> 7, k = i & 127;
  const float* W = which == 0 ? W0 : (which == 1 ? W1 : W2);
  float v = W[k * 128 + nn];
  if (which == 0) {
    Wt0[nn * 128 + k] = f2bf(v);
  } else {
    (which == 1 ? Wt1 : Wt2)[nn * 128 + k] = f2h(v);
  }
}

// ---------------- Aggregate (f16 table, pk_fma_f16, tail-predicated) --
// One wave per node, quarter-split gathers. Full 16-edge steps issue 4
// independent dwordx4 gathers; the wave-uniform tail issues ceil(r/4).
// Accumulation: packed f16 (1 v_pk_fma_f16 per gathered dword); each
// quarter-lane accumulates only ~deg/4 terms in f16, cross-quarter
// reduce in f32. mode 0: out f16. 1: +resid f16. 2: out f32 (final).
__global__ __launch_bounds__(256) void aggregate_kernel(
    const unsigned short* __restrict__ hWb, const int* __restrict__ row_ptr,
    const unsigned int* __restrict__ colw, const float* __restrict__ dinv,
    const float* __restrict__ bias, const unsigned int* __restrict__ resid16,
    void* __restrict__ out, int n, int mode) {
  int node = blockIdx.x * 4 + (threadIdx.x >> 6);
  int lane = threadIdx.x & 63;
  if (node >= n) return;  // wave-uniform
  int q = lane >> 4;      // quarter: which edge of the 4-pack
  int l15 = lane & 15;
  int lb = l15 * 16;      // byte offset within a 256B row
  const char* hWbc = (const char*)hWb;
  int beg = row_ptr[node], end = row_ptr[node + 1];
  const float WQI = 1.0f / 32767.0f;

  // hoisted independent loads: self row word, bias, resid, dinv
  unsigned int su =
      *(const unsigned int*)(hWbc + (size_t)node * 256 + (unsigned)(lb + q * 4));
  f32x2 bv = ((const f32x2*)bias)[l15 * 4 + q];
  size_t oidx = (size_t)node * 64 + (unsigned)(l15 * 4 + q);
  float rx = 0.0f, ry = 0.0f;
  if (mode >= 1) {
    unsigned int rv = __builtin_nontemporal_load(&resid16[oidx]);
    h16x2 rh = u2h2((int)rv);
    rx = (float)rh.x; ry = (float)rh.y;
  }
  float di = dinv[node];

  h16x2 acch[4];
  #pragma unroll
  for (int m = 0; m < 4; ++m) acch[m] = (h16x2){(_Float16)0.0f, (_Float16)0.0f};

  for (int cbeg = beg; cbeg < end; cbeg += 64) {
    int cnt = end - cbeg; if (cnt > 64) cnt = 64;
    unsigned int pk = 0;                 // lanes >= cnt: row 0, weight 0
    if (lane < cnt) pk = __builtin_nontemporal_load(&colw[cbeg + lane]);
    unsigned int bo = (pk >> 15) << 8;   // row byte offset (s * 256)
    float wv = (float)(pk & 0x7fffu) * WQI;
    unsigned int wh = f2h(wv);
    int wpk = (int)((wh << 16) | wh);    // (w,w) half2

    int j = 0;
    for (; j + 16 <= cnt; j += 16) {
      unsigned int b0 = (unsigned int)__shfl((int)bo, j + 0 + q, 64);
      unsigned int b1 = (unsigned int)__shfl((int)bo, j + 4 + q, 64);
      unsigned int b2 = (unsigned int)__shfl((int)bo, j + 8 + q, 64);
      unsigned int b3 = (unsigned int)__shfl((int)bo, j + 12 + q, 64);
      int w0 = __shfl(wpk, j + 0 + q, 64);
      int w1 = __shfl(wpk, j + 4 + q, 64);
      int w2 = __shfl(wpk, j + 8 + q, 64);
      int w3 = __shfl(wpk, j + 12 + q, 64);
      // 4 independent gathers, issued back-to-back
      i32x4 p0 = *(const i32x4*)(hWbc + (b0 + (unsigned int)lb));
      i32x4 p1 = *(const i32x4*)(hWbc + (b1 + (unsigned int)lb));
      i32x4 p2 = *(const i32x4*)(hWbc + (b2 + (unsigned int)lb));
      i32x4 p3 = *(const i32x4*)(hWbc + (b3 + (unsigned int)lb));
      h16x2 h0 = u2h2(w0), h1 = u2h2(w1), h2 = u2h2(w2), h3 = u2h2(w3);
      #pragma unroll
      for (int m = 0; m < 4; ++m) acch[m] += h0 * u2h2(p0[m]);
      #pragma unroll
      for (int m = 0; m < 4; ++m) acch[m] += h1 * u2h2(p1[m]);
      #pragma unroll
      for (int m = 0; m < 4; ++m) acch[m] += h2 * u2h2(p2[m]);
      #pragma unroll
      for (int m = 0; m < 4; ++m) acch[m] += h3 * u2h2(p3[m]);
    }
    int r = cnt - j;  // 0..15, wave-uniform
    if (r > 0) {
      unsigned int bA, bB = 0, bC = 0, bD = 0;
      int wA, wB = 0, wC = 0, wD = 0;
      bA = (unsigned int)__shfl((int)bo, j + 0 + q, 64);
      wA = __shfl(wpk, j + 0 + q, 64);
      if (r > 4) {
        bB = (unsigned int)__shfl((int)bo, j + 4 + q, 64);
        wB = __shfl(wpk, j + 4 + q, 64);
      }
      if (r > 8) {
        bC = (unsigned int)__shfl((int)bo, j + 8 + q, 64);
        wC = __shfl(wpk, j + 8 + q, 64);
      }
      if (r > 12) {
        bD = (unsigned int)__shfl((int)bo, j + 12 + q, 64);
        wD = __shfl(wpk, j + 12 + q, 64);
      }
      i32x4 pA, pB, pC, pD;
      pA = *(const i32x4*)(hWbc + (bA + (unsigned int)lb));
      if (r > 4)  pB = *(const i32x4*)(hWbc + (bB + (unsigned int)lb));
      if (r > 8)  pC = *(const i32x4*)(hWbc + (bC + (unsigned int)lb));
      if (r > 12) pD = *(const i32x4*)(hWbc + (bD + (unsigned int)lb));
      h16x2 hA = u2h2(wA);
      #pragma unroll
      for (int m = 0; m < 4; ++m) acch[m] += hA * u2h2(pA[m]);
      if (r > 4) {
        h16x2 hB = u2h2(wB);
        #pragma unroll
        for (int m = 0; m < 4; ++m) acch[m] += hB * u2h2(pB[m]);
      }
      if (r > 8) {
        h16x2 hC = u2h2(wC);
        #pragma unroll
        for (int m = 0; m < 4; ++m) acch[m] += hC * u2h2(pC[m]);
      }
      if (r > 12) {
        h16x2 hD = u2h2(wD);
        #pragma unroll
        for (int m = 0; m < 4; ++m) acch[m] += hD * u2h2(pD[m]);
      }
    }
  }

  // f16 -> f32, then reduce across the 4 quarters
  f32x2 acc2[4];
  #pragma unroll
  for (int m = 0; m < 4; ++m) {
    acc2[m].x = (float)acch[m].x;
    acc2[m].y = (float)acch[m].y;
  }
  #pragma unroll
  for (int m = 0; m < 4; ++m) {
    acc2[m].x += __shfl_xor(acc2[m].x, 16, 64);
    acc2[m].x += __shfl_xor(acc2[m].x, 32, 64);
    acc2[m].y += __shfl_xor(acc2[m].y, 16, 64);
    acc2[m].y += __shfl_xor(acc2[m].y, 32, 64);
  }

  // epilogue, all 64 lanes active: quarter q owns columns 2q, 2q+1 of
  // this lane's 8-column slice
  float sx = 0.0f, sy = 0.0f;
  #pragma unroll
  for (int k = 0; k < 4; ++k) {
    if (q == k) { sx = acc2[k].x; sy = acc2[k].y; }
  }
  h16x2 sh = u2h2((int)su);
  float dii = di * di;
  float ax = sx + dii * (float)sh.x + bv.x + rx;
  float ay = sy + dii * (float)sh.y + bv.y + ry;
  float ox = ax > 0.0f ? ax : expm1f(ax);
  float oy = ay > 0.0f ? ay : expm1f(ay);
  if (mode == 2) {
    f32x2 o; o.x = ox; o.y = oy;
    __builtin_nontemporal_store(o, &((f32x2*)out)[oidx]);
  } else {
    unsigned int pk2 = ((unsigned int)f2h(oy) << 16) | f2h(ox);
    __builtin_nontemporal_store(pk2, &((unsigned int*)out)[oidx]);
  }
}

extern "C" void kernel_launch(void* const* d_in, const int* in_sizes, int n_in,
                              void* d_out, int out_size, void* d_ws, size_t ws_size,
                              hipStream_t stream) {
  const float* x  = (const float*)d_in[0];
  const int* eidx = (const int*)d_in[1];
  const float* W0 = (const float*)d_in[2];
  const float* b0 = (const float*)d_in[3];
  const float* W1 = (const float*)d_in[4];
  const float* b1 = (const float*)d_in[5];
  const float* W2 = (const float*)d_in[6];
  const float* b2 = (const float*)d_in[7];
  float* outp = (float*)d_out;

  const int N = in_sizes[0] / NFEAT;   // 100000
  const int E = in_sizes[1] / 2;       // 1600000 (divisible by 4)
  const int* src = eidx;
  const int* dst = eidx + E;
  const int NBUC = (N + BWID - 1) >> BSH;  // 196
  const int e4 = E / 4;

  // workspace layout (all chunk sizes 1KB-multiples)
  const size_t S1 = 401408;                   // > (N+1)*4
  const size_t SBK = 1024;                    // > (NBUC+1)*4
  const size_t SW = 32768;                    // 128*128*2
  const size_t SE = (size_t)E * 4;            // 6.4 MB packed edges
  const size_t SEB = (size_t)E * 8;           // 12.8 MB bucketed (dst,src)
  const size_t SH = (size_t)N * NFEAT * 2;    // 25.6 MB f16 features
  char* p = (char*)d_ws;
  float* dinv   = (float*)p;            p += S1;
  int*   rowp   = (int*)p;              p += S1;
  int*   bcnt   = (int*)p;              p += SBK;
  int*   boff   = (int*)p;              p += SBK;
  int*   gcur   = (int*)p;              p += SBK;
  unsigned short* Wt0 = (unsigned short*)p;  p += SW;  // bf16
  unsigned short* Wt1 = (unsigned short*)p;  p += SW;  // f16
  unsigned short* Wt2 = (unsigned short*)p;  p += SW;  // f16
  unsigned int* colw = (unsigned int*)p; p += SE;
  unsigned long long* ebuf = (unsigned long long*)p; p += SEB;
  unsigned short* hWb = (unsigned short*)p;  p += SH;  // f16 gather table
  unsigned short* hA  = (unsigned short*)p;  p += SH;  // f16 h
  unsigned short* hB  = (unsigned short*)p;  p += SH;  // f16 h

  int gemm_blocks = (N + 63) / 64;        // 1563
  int cbk = (e4 + 1023) / 1024;           // 391 (4096 edges/block)
  int agg_blocks = (N + 3) / 4;

  // ---- prep + fused {gemm0, Pass A} ----
  wprep_kernel<<<192, 256, 0, stream>>>(W0, W1, W2, Wt0, Wt1, Wt2);
  hipMemsetAsync(bcnt, 0, (size_t)NBUC * 4, stream);
  fused_g0_hist_kernel<<<gemm_blocks + cbk, 256, 0, stream>>>(
      x, Wt0, hWb, N, gemm_blocks, (const int4*)dst, bcnt, e4, NBUC);

  // ---- bucketed CSR build ----
  scan_buckets_kernel<<<1, 256, 0, stream>>>(bcnt, boff, gcur, rowp,
                                             NBUC, N, E);
  bucket_scatter_kernel<<<cbk, 256, 0, stream>>>(
      (const int4*)src, (const int4*)dst, gcur, ebuf, e4);
  bucket_deg_kernel<<<NBUC, 256, 0, stream>>>(ebuf, boff, rowp, dinv, N);
  bucket_fill_kernel<<<NBUC, 256, 0, stream>>>(ebuf, boff, rowp, dinv,
                                               colw, N);

  // ---- layer 0 aggregate (gemm0 already done): out hA f16 ----
  aggregate_kernel<<<agg_blocks, 256, 0, stream>>>(
      hWb, rowp, colw, dinv, b0, nullptr, hA, N, 0);
  // ---- layer 1 ----
  gemm_f16_kernel<<<gemm_blocks, 256, 0, stream>>>(hA, Wt1, hWb, N);
  aggregate_kernel<<<agg_blocks, 256, 0, stream>>>(
      hWb, rowp, colw, dinv, b1, (const unsigned int*)hA, hB, N, 1);
  // ---- layer 2, write d_out f32 ----
  gemm_f16_kernel<<<gemm_blocks, 256, 0, stream>>>(hB, Wt2, hWb, N);
  aggregate_kernel<<<agg_blocks, 256, 0, stream>>>(
      hWb, rowp, colw, dinv, b2, (const unsigned int*)hB, outp, N, 2);
}

// Round 8
// 449.602 us; speedup vs baseline: 1.2194x; 1.0030x over previous
//
#include <hip/hip_runtime.h>
#include <math.h>

// GCN: h = elu(D^-1/2 (A+I) D^-1/2 (h W) + b [+ resid])
// N=100000 nodes, E=1600000 edges, 128 features per layer.
//
// R15 changes vs R14 (451us, agg 65.2us @ VALU 46%, FETCH 201MB):
//  Model: dur ~= VALU + ~35us memory term (fits R9/R10/R14). Remaining
//  VALU is dominated by the per-node EPILOGUE (~90 wave-instrs vs ~34
//  inner-loop instrs at deg~17):
//  - expm1f (libm polynomial, ~35 instrs x2) -> __expf(x)-1 (v_exp_f32,
//    ~3 instrs). Abs error ~2^-22, invisible vs 0.0078 budget.
//  - Quarter-reduce in packed f16: shfl_xor on h16x2 bits + v_pk_add_f16
//    (8+8 ops) + one 4-way int select, replacing 8 cvt + 16 f32 shfl +
//    16 add + 8 selects. Added error ~2^-11 scale << 2^-7 floor (floor
//    comes from layer-0 bf16 input staging, unchanged).

#define NFEAT 128
#define LDSP 136   // LDS row pitch in shorts (128 + 8 pad)
#define BSH 9      // bucket shift: 512 nodes/bucket
#define BWID 512

typedef short short8 __attribute__((ext_vector_type(8)));
typedef unsigned short ushort8 __attribute__((ext_vector_type(8)));
typedef _Float16 half8 __attribute__((ext_vector_type(8)));
typedef _Float16 h16x2 __attribute__((ext_vector_type(2)));
typedef float f32x4 __attribute__((ext_vector_type(4)));
typedef float f32x2 __attribute__((ext_vector_type(2)));
typedef int i32x4 __attribute__((ext_vector_type(4)));

static __device__ __forceinline__ unsigned short f2bf(float f) {
  union { float f; unsigned int u; } v; v.f = f;
  unsigned int r = v.u + 0x7fffu + ((v.u >> 16) & 1u);  // RNE (finite values)
  return (unsigned short)(r >> 16);
}
static __device__ __forceinline__ unsigned short f2h(float f) {
  union { _Float16 h; unsigned short u; } c; c.h = (_Float16)f; return c.u;
}
static __device__ __forceinline__ h16x2 u2h2(int u) {
  union { int i; h16x2 h; } c; c.i = u; return c.h;
}
static __device__ __forceinline__ int h22u(h16x2 h) {
  union { h16x2 h; int i; } c; c.h = h; return c.i;
}
static __device__ __forceinline__ float elu_fast(float a) {
  return a > 0.0f ? a : (__expf(a) - 1.0f);
}

// ---------------- GEMM body, fp32 input -> bf16 MFMA, f16 out (L0) ----
static __device__ __forceinline__ void gemm_body(
    int gblk, const float* __restrict__ h, const unsigned short* __restrict__ Wt,
    unsigned short* __restrict__ out, int n, unsigned short* lds) {
  int t = threadIdx.x;
  int block0 = gblk * 64;

  const f32x4* h4 = (const f32x4*)h;
  #pragma unroll
  for (int i = 0; i < 8; ++i) {
    int idx = t + 256 * i;          // 0..2047
    int r = idx >> 5, c = idx & 31; // row, float4-col
    int grow = block0 + r; if (grow >= n) grow = n - 1;
    f32x4 v = __builtin_nontemporal_load(&h4[(size_t)grow * 32 + c]);
    ushort4 b;
    b.x = f2bf(v.x); b.y = f2bf(v.y); b.z = f2bf(v.z); b.w = f2bf(v.w);
    *(ushort4*)&lds[r * LDSP + c * 4] = b;
  }
  __syncthreads();

  int lane = t & 63, wave = t >> 6;
  int row16 = lane & 15;
  int kgrp = lane >> 4;

  short8 afrag[4];
  #pragma unroll
  for (int ks = 0; ks < 4; ++ks)
    afrag[ks] =
        *(const short8*)&lds[(wave * 16 + row16) * LDSP + ks * 32 + kgrp * 8];

  f32x4 acc[8];
  #pragma unroll
  for (int ct = 0; ct < 8; ++ct) {
    acc[ct] = (f32x4){0.0f, 0.0f, 0.0f, 0.0f};
    const short8* wrow =
        (const short8*)(Wt + (size_t)(ct * 16 + row16) * NFEAT);
    #pragma unroll
    for (int ks = 0; ks < 4; ++ks) {
      acc[ct] = __builtin_amdgcn_mfma_f32_16x16x32_bf16(
          wrow[ks * 4 + kgrp], afrag[ks], acc[ct], 0, 0, 0);
    }
  }

  int orow = block0 + wave * 16 + row16;
  if (orow < n) {
    unsigned short* op = out + (size_t)orow * NFEAT + kgrp * 4;
    #pragma unroll
    for (int ct = 0; ct < 8; ++ct) {
      ushort4 o;
      o.x = f2h(acc[ct][0]); o.y = f2h(acc[ct][1]);
      o.z = f2h(acc[ct][2]); o.w = f2h(acc[ct][3]);
      *(ushort4*)(op + ct * 16) = o;
    }
  }
}

// ---------------- GEMM, f16 input -> f16 MFMA, f16 out (L1, L2) -------
__global__ __launch_bounds__(256) void gemm_f16_kernel(
    const unsigned short* __restrict__ h16,  // f16 bits [n][128]
    const unsigned short* __restrict__ Wt,   // f16 bits [128][128] (n-major)
    unsigned short* __restrict__ out, int n) {
  __shared__ int lds_i[64 * LDSP / 2];
  unsigned short* lds = (unsigned short*)lds_i;
  int t = threadIdx.x;
  int block0 = blockIdx.x * 64;

  const ushort8* h8 = (const ushort8*)h16;
  #pragma unroll
  for (int i = 0; i < 4; ++i) {
    int idx = t + 256 * i;          // 0..1023
    int r = idx >> 4, c = idx & 15; // row, 8-elem col
    int grow = block0 + r; if (grow >= n) grow = n - 1;
    ushort8 v = __builtin_nontemporal_load(&h8[(size_t)grow * 16 + c]);
    *(ushort8*)&lds[r * LDSP + c * 8] = v;
  }
  __syncthreads();

  int lane = t & 63, wave = t >> 6;
  int row16 = lane & 15;
  int kgrp = lane >> 4;

  half8 afrag[4];
  #pragma unroll
  for (int ks = 0; ks < 4; ++ks)
    afrag[ks] =
        *(const half8*)&lds[(wave * 16 + row16) * LDSP + ks * 32 + kgrp * 8];

  f32x4 acc[8];
  #pragma unroll
  for (int ct = 0; ct < 8; ++ct) {
    acc[ct] = (f32x4){0.0f, 0.0f, 0.0f, 0.0f};
    const half8* wrow =
        (const half8*)(Wt + (size_t)(ct * 16 + row16) * NFEAT);
    #pragma unroll
    for (int ks = 0; ks < 4; ++ks) {
      acc[ct] = __builtin_amdgcn_mfma_f32_16x16x32_f16(
          wrow[ks * 4 + kgrp], afrag[ks], acc[ct], 0, 0, 0);
    }
  }

  int orow = block0 + wave * 16 + row16;
  if (orow < n) {
    unsigned short* op = out + (size_t)orow * NFEAT + kgrp * 4;
    #pragma unroll
    for (int ct = 0; ct < 8; ++ct) {
      ushort4 o;
      o.x = f2h(acc[ct][0]); o.y = f2h(acc[ct][1]);
      o.z = f2h(acc[ct][2]); o.w = f2h(acc[ct][3]);
      *(ushort4*)(op + ct * 16) = o;
    }
  }
}

// gemm0 fused with Pass A (bucket histogram) — independent work.
__global__ __launch_bounds__(256) void fused_g0_hist_kernel(
    const float* __restrict__ x, const unsigned short* __restrict__ Wt0,
    unsigned short* __restrict__ hWb, int n, int gb,
    const int4* __restrict__ dst4, int* __restrict__ bcnt, int e4, int nbuc) {
  __shared__ int lds_i[64 * LDSP / 2];
  int t = threadIdx.x;
  if ((int)blockIdx.x < gb) {
    gemm_body(blockIdx.x, x, Wt0, hWb, n, (unsigned short*)lds_i);
  } else {
    int* hist = lds_i;
    hist[t] = 0;
    __syncthreads();
    int base = ((int)blockIdx.x - gb) * 1024;
    #pragma unroll
    for (int i = 0; i < 4; ++i) {
      int idx = base + t + 256 * i;
      if (idx < e4) {
        int4 d = dst4[idx];
        atomicAdd(&hist[d.x >> BSH], 1);
        atomicAdd(&hist[d.y >> BSH], 1);
        atomicAdd(&hist[d.z >> BSH], 1);
        atomicAdd(&hist[d.w >> BSH], 1);
      }
    }
    __syncthreads();
    int h = hist[t];
    if (t < nbuc && h) atomicAdd(&bcnt[t], h);
  }
}

// Pass B: exclusive scan of bucket counts (nbuc <= 256), init gcur, rowp[n]=E
__global__ __launch_bounds__(256) void scan_buckets_kernel(
    const int* __restrict__ bcnt, int* __restrict__ boff,
    int* __restrict__ gcur, int* __restrict__ rowp, int nbuc, int n, int e) {
  __shared__ int wsum[4];
  int t = threadIdx.x, lane = t & 63, wid = t >> 6;
  int v = (t < nbuc) ? bcnt[t] : 0;
  int s = v;
  #pragma unroll
  for (int off = 1; off < 64; off <<= 1) {
    int u = __shfl_up(s, off, 64);
    if (lane >= off) s += u;
  }
  if (lane == 63) wsum[wid] = s;
  __syncthreads();
  int add = 0;
  for (int w = 0; w < wid; ++w) add += wsum[w];
  int incl = add + s;
  if (t < nbuc) { boff[t] = incl - v; gcur[t] = incl - v; }
  if (t == nbuc - 1) boff[nbuc] = incl;  // == E
  if (t == 0) rowp[n] = e;
}

// Pass C: scatter (dst,src) u64 into bucket-major ebuf, block-chunked.
__global__ __launch_bounds__(256) void bucket_scatter_kernel(
    const int4* __restrict__ src4, const int4* __restrict__ dst4,
    int* __restrict__ gcur, unsigned long long* __restrict__ ebuf, int e4) {
  __shared__ int hist[256];
  __shared__ int cbase[256];
  __shared__ int cur[256];
  int t = threadIdx.x;
  hist[t] = 0; cur[t] = 0;
  __syncthreads();
  int base = blockIdx.x * 1024;
  int4 dv[4], sv[4];
  bool val[4];
  #pragma unroll
  for (int i = 0; i < 4; ++i) {
    int idx = base + t + 256 * i;
    val[i] = idx < e4;
    if (val[i]) {
      dv[i] = dst4[idx];
      sv[i] = src4[idx];
      atomicAdd(&hist[dv[i].x >> BSH], 1);
      atomicAdd(&hist[dv[i].y >> BSH], 1);
      atomicAdd(&hist[dv[i].z >> BSH], 1);
      atomicAdd(&hist[dv[i].w >> BSH], 1);
    }
  }
  __syncthreads();
  int h = hist[t];
  if (h) cbase[t] = atomicAdd(&gcur[t], h);  // hist[t]==0 for t>=nbuc
  __syncthreads();
  #pragma unroll
  for (int i = 0; i < 4; ++i) {
    if (val[i]) {
      int d, s, b, p;
      d = dv[i].x; s = sv[i].x; b = d >> BSH;
      p = cbase[b] + atomicAdd(&cur[b], 1);
      ebuf[p] = ((unsigned long long)(unsigned)d << 32) | (unsigned)s;
      d = dv[i].y; s = sv[i].y; b = d >> BSH;
      p = cbase[b] + atomicAdd(&cur[b], 1);
      ebuf[p] = ((unsigned long long)(unsigned)d << 32) | (unsigned)s;
      d = dv[i].z; s = sv[i].z; b = d >> BSH;
      p = cbase[b] + atomicAdd(&cur[b], 1);
      ebuf[p] = ((unsigned long long)(unsigned)d << 32) | (unsigned)s;
      d = dv[i].w; s = sv[i].w; b = d >> BSH;
      p = cbase[b] + atomicAdd(&cur[b], 1);
      ebuf[p] = ((unsigned long long)(unsigned)d << 32) | (unsigned)s;
    }
  }
}

// Pass D1: per-bucket degree hist (LDS) + local scan -> rowp, dinv.
__global__ __launch_bounds__(256) void bucket_deg_kernel(
    const unsigned long long* __restrict__ ebuf, const int* __restrict__ boff,
    int* __restrict__ rowp, float* __restrict__ dinv, int n) {
  __shared__ int deg[BWID];
  __shared__ int wsum[4];
  int t = threadIdx.x;
  int b = blockIdx.x, node0 = b << BSH;
  deg[t] = 0; deg[t + 256] = 0;
  __syncthreads();
  int ebeg = boff[b], eend = boff[b + 1];
  for (int i = ebeg + t; i < eend; i += 256) {
    int d = (int)(ebuf[i] >> 32);
    atomicAdd(&deg[d - node0], 1);
  }
  __syncthreads();
  int d0 = deg[2 * t], d1 = deg[2 * t + 1];
  int s = d0 + d1;
  int lane = t & 63, wid = t >> 6;
  int sc = s;
  #pragma unroll
  for (int off = 1; off < 64; off <<= 1) {
    int u = __shfl_up(sc, off, 64);
    if (lane >= off) sc += u;
  }
  if (lane == 63) wsum[wid] = sc;
  __syncthreads();
  int add = 0;
  for (int w = 0; w < wid; ++w) add += wsum[w];
  int excl = ebeg + add + sc - s;  // rowp of node 2t in this bucket
  int node = node0 + 2 * t;
  if (node < n) {
    rowp[node] = excl;
    dinv[node] = rsqrtf(1.0f + (float)d0);
  }
  if (node + 1 < n) {
    rowp[node + 1] = excl + d0;
    dinv[node + 1] = rsqrtf(1.0f + (float)d1);
  }
}

// Pass D2: per-bucket fine scatter into colw (writes confined to the
// bucket's ~32KB region -> one block/XCD -> L2 lines merge fully).
__global__ __launch_bounds__(256) void bucket_fill_kernel(
    const unsigned long long* __restrict__ ebuf, const int* __restrict__ boff,
    const int* __restrict__ rowp, const float* __restrict__ dinv,
    unsigned int* __restrict__ colw, int n) {
  __shared__ int cur[BWID];
  int t = threadIdx.x;
  int b = blockIdx.x, node0 = b << BSH;
  for (int k = t; k < BWID; k += 256) {
    int node = node0 + k;
    cur[k] = (node < n) ? rowp[node] : 0;
  }
  __syncthreads();
  int ebeg = boff[b], eend = boff[b + 1];
  for (int i = ebeg + t; i < eend; i += 256) {
    unsigned long long p = ebuf[i];
    int d = (int)(p >> 32);
    int s = (int)(unsigned int)p;
    float w = dinv[s] * dinv[d];
    unsigned int wq = (unsigned int)(w * 32767.0f + 0.5f);
    int pos = atomicAdd(&cur[d - node0], 1);
    colw[pos] = ((unsigned int)s << 15) | wq;
  }
}

// W fp32 [k][n] -> Wt0 bf16 [n][k]; Wt1/Wt2 f16 [n][k]
__global__ __launch_bounds__(256) void wprep_kernel(
    const float* __restrict__ W0, const float* __restrict__ W1,
    const float* __restrict__ W2, unsigned short* __restrict__ Wt0,
    unsigned short* __restrict__ Wt1, unsigned short* __restrict__ Wt2) {
  int which = blockIdx.x >> 6;
  int i = (blockIdx.x & 63) * 256 + threadIdx.x;
  int nn = i >> 7, k = i & 127;
  const float* W = which == 0 ? W0 : (which == 1 ? W1 : W2);
  float v = W[k * 128 + nn];
  if (which == 0) {
    Wt0[nn * 128 + k] = f2bf(v);
  } else {
    (which == 1 ? Wt1 : Wt2)[nn * 128 + k] = f2h(v);
  }
}

// ---------------- Aggregate (f16 table, pk_fma_f16, packed reduce) ----
// One wave per node, quarter-split gathers. Full 16-edge steps issue 4
// independent dwordx4 gathers; the wave-uniform tail issues ceil(r/4).
// Accumulation: packed f16; quarter-reduce also packed f16 (shfl_xor on
// bits + v_pk_add_f16). ELU via v_exp_f32 (__expf), not libm expm1f.
// mode 0: out f16. 1: +resid f16. 2: out f32 (final).
__global__ __launch_bounds__(256) void aggregate_kernel(
    const unsigned short* __restrict__ hWb, const int* __restrict__ row_ptr,
    const unsigned int* __restrict__ colw, const float* __restrict__ dinv,
    const float* __restrict__ bias, const unsigned int* __restrict__ resid16,
    void* __restrict__ out, int n, int mode) {
  int node = blockIdx.x * 4 + (threadIdx.x >> 6);
  int lane = threadIdx.x & 63;
  if (node >= n) return;  // wave-uniform
  int q = lane >> 4;      // quarter: which edge of the 4-pack
  int l15 = lane & 15;
  int lb = l15 * 16;      // byte offset within a 256B row
  const char* hWbc = (const char*)hWb;
  int beg = row_ptr[node], end = row_ptr[node + 1];
  const float WQI = 1.0f / 32767.0f;

  // hoisted independent loads: self row word, bias, resid, dinv
  unsigned int su =
      *(const unsigned int*)(hWbc + (size_t)node * 256 + (unsigned)(lb + q * 4));
  f32x2 bv = ((const f32x2*)bias)[l15 * 4 + q];
  size_t oidx = (size_t)node * 64 + (unsigned)(l15 * 4 + q);
  float rx = 0.0f, ry = 0.0f;
  if (mode >= 1) {
    unsigned int rv = __builtin_nontemporal_load(&resid16[oidx]);
    h16x2 rh = u2h2((int)rv);
    rx = (float)rh.x; ry = (float)rh.y;
  }
  float di = dinv[node];

  h16x2 acch[4];
  #pragma unroll
  for (int m = 0; m < 4; ++m) acch[m] = (h16x2){(_Float16)0.0f, (_Float16)0.0f};

  for (int cbeg = beg; cbeg < end; cbeg += 64) {
    int cnt = end - cbeg; if (cnt > 64) cnt = 64;
    unsigned int pk = 0;                 // lanes >= cnt: row 0, weight 0
    if (lane < cnt) pk = __builtin_nontemporal_load(&colw[cbeg + lane]);
    unsigned int bo = (pk >> 15) << 8;   // row byte offset (s * 256)
    float wv = (float)(pk & 0x7fffu) * WQI;
    unsigned int wh = f2h(wv);
    int wpk = (int)((wh << 16) | wh);    // (w,w) half2

    int j = 0;
    for (; j + 16 <= cnt; j += 16) {
      unsigned int b0 = (unsigned int)__shfl((int)bo, j + 0 + q, 64);
      unsigned int b1 = (unsigned int)__shfl((int)bo, j + 4 + q, 64);
      unsigned int b2 = (unsigned int)__shfl((int)bo, j + 8 + q, 64);
      unsigned int b3 = (unsigned int)__shfl((int)bo, j + 12 + q, 64);
      int w0 = __shfl(wpk, j + 0 + q, 64);
      int w1 = __shfl(wpk, j + 4 + q, 64);
      int w2 = __shfl(wpk, j + 8 + q, 64);
      int w3 = __shfl(wpk, j + 12 + q, 64);
      // 4 independent gathers, issued back-to-back
      i32x4 p0 = *(const i32x4*)(hWbc + (b0 + (unsigned int)lb));
      i32x4 p1 = *(const i32x4*)(hWbc + (b1 + (unsigned int)lb));
      i32x4 p2 = *(const i32x4*)(hWbc + (b2 + (unsigned int)lb));
      i32x4 p3 = *(const i32x4*)(hWbc + (b3 + (unsigned int)lb));
      h16x2 h0 = u2h2(w0), h1 = u2h2(w1), h2 = u2h2(w2), h3 = u2h2(w3);
      #pragma unroll
      for (int m = 0; m < 4; ++m) acch[m] += h0 * u2h2(p0[m]);
      #pragma unroll
      for (int m = 0; m < 4; ++m) acch[m] += h1 * u2h2(p1[m]);
      #pragma unroll
      for (int m = 0; m < 4; ++m) acch[m] += h2 * u2h2(p2[m]);
      #pragma unroll
      for (int m = 0; m < 4; ++m) acch[m] += h3 * u2h2(p3[m]);
    }
    int r = cnt - j;  // 0..15, wave-uniform
    if (r > 0) {
      unsigned int bA, bB = 0, bC = 0, bD = 0;
      int wA, wB = 0, wC = 0, wD = 0;
      bA = (unsigned int)__shfl((int)bo, j + 0 + q, 64);
      wA = __shfl(wpk, j + 0 + q, 64);
      if (r > 4) {
        bB = (unsigned int)__shfl((int)bo, j + 4 + q, 64);
        wB = __shfl(wpk, j + 4 + q, 64);
      }
      if (r > 8) {
        bC = (unsigned int)__shfl((int)bo, j + 8 + q, 64);
        wC = __shfl(wpk, j + 8 + q, 64);
      }
      if (r > 12) {
        bD = (unsigned int)__shfl((int)bo, j + 12 + q, 64);
        wD = __shfl(wpk, j + 12 + q, 64);
      }
      i32x4 pA, pB, pC, pD;
      pA = *(const i32x4*)(hWbc + (bA + (unsigned int)lb));
      if (r > 4)  pB = *(const i32x4*)(hWbc + (bB + (unsigned int)lb));
      if (r > 8)  pC = *(const i32x4*)(hWbc + (bC + (unsigned int)lb));
      if (r > 12) pD = *(const i32x4*)(hWbc + (bD + (unsigned int)lb));
      h16x2 hA = u2h2(wA);
      #pragma unroll
      for (int m = 0; m < 4; ++m) acch[m] += hA * u2h2(pA[m]);
      if (r > 4) {
        h16x2 hB = u2h2(wB);
        #pragma unroll
        for (int m = 0; m < 4; ++m) acch[m] += hB * u2h2(pB[m]);
      }
      if (r > 8) {
        h16x2 hC = u2h2(wC);
        #pragma unroll
        for (int m = 0; m < 4; ++m) acch[m] += hC * u2h2(pC[m]);
      }
      if (r > 12) {
        h16x2 hD = u2h2(wD);
        #pragma unroll
        for (int m = 0; m < 4; ++m) acch[m] += hD * u2h2(pD[m]);
      }
    }
  }

  // quarter-reduce, packed f16: shfl_xor on bits + v_pk_add_f16
  #pragma unroll
  for (int m = 0; m < 4; ++m) {
    acch[m] += u2h2(__shfl_xor(h22u(acch[m]), 16, 64));
    acch[m] += u2h2(__shfl_xor(h22u(acch[m]), 32, 64));
  }

  // epilogue, all 64 lanes active: quarter q owns columns 2q, 2q+1 of
  // this lane's 8-column slice (= the two halves of acch[q])
  int own = h22u(acch[0]);
  #pragma unroll
  for (int k = 1; k < 4; ++k) {
    if (q == k) own = h22u(acch[k]);
  }
  h16x2 o2 = u2h2(own);
  float sx = (float)o2.x, sy = (float)o2.y;
  h16x2 sh = u2h2((int)su);
  float dii = di * di;
  float ax = sx + dii * (float)sh.x + bv.x + rx;
  float ay = sy + dii * (float)sh.y + bv.y + ry;
  float ox = elu_fast(ax);
  float oy = elu_fast(ay);
  if (mode == 2) {
    f32x2 o; o.x = ox; o.y = oy;
    __builtin_nontemporal_store(o, &((f32x2*)out)[oidx]);
  } else {
    unsigned int pk2 = ((unsigned int)f2h(oy) << 16) | f2h(ox);
    __builtin_nontemporal_store(pk2, &((unsigned int*)out)[oidx]);
  }
}

extern "C" void kernel_launch(void* const* d_in, const int* in_sizes, int n_in,
                              void* d_out, int out_size, void* d_ws, size_t ws_size,
                              hipStream_t stream) {
  const float* x  = (const float*)d_in[0];
  const int* eidx = (const int*)d_in[1];
  const float* W0 = (const float*)d_in[2];
  const float* b0 = (const float*)d_in[3];
  const float* W1 = (const float*)d_in[4];
  const float* b1 = (const float*)d_in[5];
  const float* W2 = (const float*)d_in[6];
  const float* b2 = (const float*)d_in[7];
  float* outp = (float*)d_out;

  const int N = in_sizes[0] / NFEAT;   // 100000
  const int E = in_sizes[1] / 2;       // 1600000 (divisible by 4)
  const int* src = eidx;
  const int* dst = eidx + E;
  const int NBUC = (N + BWID - 1) >> BSH;  // 196
  const int e4 = E / 4;

  // workspace layout (all chunk sizes 1KB-multiples)
  const size_t S1 = 401408;                   // > (N+1)*4
  const size_t SBK = 1024;                    // > (NBUC+1)*4
  const size_t SW = 32768;                    // 128*128*2
  const size_t SE = (size_t)E * 4;            // 6.4 MB packed edges
  const size_t SEB = (size_t)E * 8;           // 12.8 MB bucketed (dst,src)
  const size_t SH = (size_t)N * NFEAT * 2;    // 25.6 MB f16 features
  char* p = (char*)d_ws;
  float* dinv   = (float*)p;            p += S1;
  int*   rowp   = (int*)p;              p += S1;
  int*   bcnt   = (int*)p;              p += SBK;
  int*   boff   = (int*)p;              p += SBK;
  int*   gcur   = (int*)p;              p += SBK;
  unsigned short* Wt0 = (unsigned short*)p;  p += SW;  // bf16
  unsigned short* Wt1 = (unsigned short*)p;  p += SW;  // f16
  unsigned short* Wt2 = (unsigned short*)p;  p += SW;  // f16
  unsigned int* colw = (unsigned int*)p; p += SE;
  unsigned long long* ebuf = (unsigned long long*)p; p += SEB;
  unsigned short* hWb = (unsigned short*)p;  p += SH;  // f16 gather table
  unsigned short* hA  = (unsigned short*)p;  p += SH;  // f16 h
  unsigned short* hB  = (unsigned short*)p;  p += SH;  // f16 h

  int gemm_blocks = (N + 63) / 64;        // 1563
  int cbk = (e4 + 1023) / 1024;           // 391 (4096 edges/block)
  int agg_blocks = (N + 3) / 4;

  // ---- prep + fused {gemm0, Pass A} ----
  wprep_kernel<<<192, 256, 0, stream>>>(W0, W1, W2, Wt0, Wt1, Wt2);
  hipMemsetAsync(bcnt, 0, (size_t)NBUC * 4, stream);
  fused_g0_hist_kernel<<<gemm_blocks + cbk, 256, 0, stream>>>(
      x, Wt0, hWb, N, gemm_blocks, (const int4*)dst, bcnt, e4, NBUC);

  // ---- bucketed CSR build ----
  scan_buckets_kernel<<<1, 256, 0, stream>>>(bcnt, boff, gcur, rowp,
                                             NBUC, N, E);
  bucket_scatter_kernel<<<cbk, 256, 0, stream>>>(
      (const int4*)src, (const int4*)dst, gcur, ebuf, e4);
  bucket_deg_kernel<<<NBUC, 256, 0, stream>>>(ebuf, boff, rowp, dinv, N);
  bucket_fill_kernel<<<NBUC, 256, 0, stream>>>(ebuf, boff, rowp, dinv,
                                               colw, N);

  // ---- layer 0 aggregate (gemm0 already done): out hA f16 ----
  aggregate_kernel<<<agg_blocks, 256, 0, stream>>>(
      hWb, rowp, colw, dinv, b0, nullptr, hA, N, 0);
  // ---- layer 1 ----
  gemm_f16_kernel<<<gemm_blocks, 256, 0, stream>>>(hA, Wt1, hWb, N);
  aggregate_kernel<<<agg_blocks, 256, 0, stream>>>(
      hWb, rowp, colw, dinv, b1, (const unsigned int*)hA, hB, N, 1);
  // ---- layer 2, write d_out f32 ----
  gemm_f16_kernel<<<gemm_blocks, 256, 0, stream>>>(hB, Wt2, hWb, N);
  aggregate_kernel<<<agg_blocks, 256, 0, stream>>>(
      hWb, rowp, colw, dinv, b2, (const unsigned int*)hB, outp, N, 2);
}